// Round 2
// 925.401 us; speedup vs baseline: 1.0373x; 1.0373x over previous
//
#include <hip/hip_runtime.h>
#include <math.h>

// ---------------------------------------------------------------------------
// B=256, T=256, LEN=256 (audio 64 | vision 64 | text 128), RANK=24, EXT=513
// ---------------------------------------------------------------------------

typedef unsigned short ushortT;
typedef short bf16x8 __attribute__((ext_vector_type(8)));
typedef float f32x4 __attribute__((ext_vector_type(4)));

__device__ __forceinline__ unsigned int f2bf(float f) {  // RNE to bf16
  unsigned int u = __float_as_uint(f);
  u += 0x7FFFu + ((u >> 16) & 1u);
  return u >> 16;
}
__device__ __forceinline__ unsigned int pk2bf(float lo, float hi) {
  return f2bf(lo) | (f2bf(hi) << 16);
}
__device__ __forceinline__ float bf2f(ushortT u) {
  return __uint_as_float(((unsigned int)u) << 16);
}

// ------------------ generic fp32 -> bf16 convert (+K-pad) -------------------
template <int KP, int KIN>
__global__ __launch_bounds__(256) void pad_cvt_k(const float* __restrict__ src,
                                                 ushortT* __restrict__ dst, int total) {
  const int i = blockIdx.x * 256 + threadIdx.x;
  if (i >= total) return;
  if constexpr (KP == KIN) {
    dst[i] = (ushortT)f2bf(src[i]);
  } else {
    const int row = i / KP, c = i - row * KP;
    dst[i] = (c < KIN) ? (ushortT)f2bf(src[(size_t)row * KIN + c]) : (ushortT)0;
  }
}

// ---------------- text input projection GEMM (bf16 MFMA, 128x256) -----------
// Y16[M=65536, 512] = bf16( X[M,768] @ W16[512,768]^T + bias )
#define SA2 40  // LDS row stride (BK=32 + 8 pad) -> <=2-way bank alias on frag reads
__global__ __launch_bounds__(512) void gemm_text2_k(const float* __restrict__ X,
                                                    const ushortT* __restrict__ W16,
                                                    const float* __restrict__ bias,
                                                    ushortT* __restrict__ Y16) {
  const int K = 768, N = 512;
  __shared__ __align__(16) ushortT As[128 * SA2];
  __shared__ __align__(16) ushortT Bs[256 * SA2];
  // n-siblings (same m-tile) at dispatch stride 8 -> same XCD -> A L2 reuse.
  const unsigned int lin = blockIdx.x;
  const int gb = (int)(lin >> 4), rb = (int)(lin & 15);
  const int m0 = (gb * 8 + (rb & 7)) * 128;
  const int n0 = (rb >> 3) * 256;
  const int tid = threadIdx.x;
  const int wave = tid >> 6, lane = tid & 63;
  const int wr = wave >> 2, wc = wave & 3;          // 2x4 wave grid (64x64 each)
  const int lm = lane & 15, lq = lane >> 4;
  const int arow = tid >> 2, aq = (tid & 3) * 8;    // A staging: 8 fp32/thread
  const int brow = tid >> 1, bq = (tid & 1) * 16;   // B staging: 16 bf16/thread

  const float*   Xp = X + (size_t)(m0 + arow) * K + aq;
  const ushortT* Wp = W16 + (size_t)(n0 + brow) * K + bq;
  uint4* As_w = (uint4*)&As[arow * SA2 + aq];
  uint4* Bs_w = (uint4*)&Bs[brow * SA2 + bq];

  f32x4 acc[4][4];
#pragma unroll
  for (int i = 0; i < 4; i++)
#pragma unroll
    for (int j = 0; j < 4; j++) acc[i][j] = (f32x4){0.f, 0.f, 0.f, 0.f};

  for (int k0 = 0; k0 < K; k0 += 32) {
    const float4 a0 = *(const float4*)(Xp + k0);
    const float4 a1 = *(const float4*)(Xp + k0 + 4);
    const uint4 b0v = *(const uint4*)(Wp + k0);
    const uint4 b1v = *(const uint4*)(Wp + k0 + 8);
    __syncthreads();
    uint4 ao;
    ao.x = pk2bf(a0.x, a0.y); ao.y = pk2bf(a0.z, a0.w);
    ao.z = pk2bf(a1.x, a1.y); ao.w = pk2bf(a1.z, a1.w);
    As_w[0] = ao;
    Bs_w[0] = b0v;
    Bs_w[1] = b1v;
    __syncthreads();
    bf16x8 af[4], bfv[4];
#pragma unroll
    for (int mt = 0; mt < 4; mt++)
      af[mt] = *(const bf16x8*)&As[(wr * 64 + mt * 16 + lm) * SA2 + lq * 8];
#pragma unroll
    for (int nt = 0; nt < 4; nt++)
      bfv[nt] = *(const bf16x8*)&Bs[(wc * 64 + nt * 16 + lm) * SA2 + lq * 8];
#pragma unroll
    for (int mt = 0; mt < 4; mt++)
#pragma unroll
      for (int nt = 0; nt < 4; nt++)
        acc[mt][nt] = __builtin_amdgcn_mfma_f32_16x16x32_bf16(af[mt], bfv[nt], acc[mt][nt], 0, 0, 0);
  }
  float biasv[4];
#pragma unroll
  for (int nt = 0; nt < 4; nt++) biasv[nt] = bias[n0 + wc * 64 + nt * 16 + lm];
#pragma unroll
  for (int mt = 0; mt < 4; mt++) {
#pragma unroll
    for (int nt = 0; nt < 4; nt++) {
      const int row0 = m0 + wr * 64 + mt * 16 + lq * 4;
      const int col = n0 + wc * 64 + nt * 16 + lm;
#pragma unroll
      for (int r = 0; r < 4; r++)
        Y16[(size_t)(row0 + r) * N + col] = (ushortT)f2bf(acc[mt][nt][r] + biasv[nt]);
    }
  }
}

// ------------- audio/vision input projection (small-K bf16 MFMA) ------------
template <int KP>
__global__ __launch_bounds__(256) void gemm_xp_k(const ushortT* __restrict__ A16,
                                                 const ushortT* __restrict__ B16,
                                                 const float* __restrict__ bias,
                                                 ushortT* __restrict__ Y16) {
  constexpr int SB = KP + 8;
  __shared__ __align__(16) ushortT As[128 * SB];
  __shared__ __align__(16) ushortT Bs[128 * SB];
  const int n0 = blockIdx.x * 128;
  const int m0 = blockIdx.y * 128;
  const int tid = threadIdx.x;
  const int srow = tid >> 1, shalf = tid & 1;
  const int wave = tid >> 6, lane = tid & 63;
  const int wr = wave >> 1, wc = wave & 1;
  const int lm = lane & 15, lq = lane >> 4;

  const uint4* ap = (const uint4*)(A16 + (size_t)(m0 + srow) * KP + shalf * (KP / 2));
  const uint4* bp = (const uint4*)(B16 + (size_t)(n0 + srow) * KP + shalf * (KP / 2));
  uint4* aw = (uint4*)&As[srow * SB + shalf * (KP / 2)];
  uint4* bw = (uint4*)&Bs[srow * SB + shalf * (KP / 2)];
#pragma unroll
  for (int i = 0; i < KP / 16; i++) { aw[i] = ap[i]; bw[i] = bp[i]; }
  __syncthreads();

  constexpr int KC = KP / 32;
  f32x4 acc[4][4];
#pragma unroll
  for (int i = 0; i < 4; i++)
#pragma unroll
    for (int j = 0; j < 4; j++) acc[i][j] = (f32x4){0.f, 0.f, 0.f, 0.f};
#pragma unroll
  for (int ks = 0; ks < KC; ks++) {
    bf16x8 af[4], bfv[4];
#pragma unroll
    for (int mt = 0; mt < 4; mt++)
      af[mt] = *(const bf16x8*)&As[(wr * 64 + mt * 16 + lm) * SB + ks * 32 + lq * 8];
#pragma unroll
    for (int nt = 0; nt < 4; nt++)
      bfv[nt] = *(const bf16x8*)&Bs[(wc * 64 + nt * 16 + lm) * SB + ks * 32 + lq * 8];
#pragma unroll
    for (int mt = 0; mt < 4; mt++)
#pragma unroll
      for (int nt = 0; nt < 4; nt++)
        acc[mt][nt] = __builtin_amdgcn_mfma_f32_16x16x32_bf16(af[mt], bfv[nt], acc[mt][nt], 0, 0, 0);
  }
  float biasv[4];
#pragma unroll
  for (int nt = 0; nt < 4; nt++) biasv[nt] = bias[n0 + wc * 64 + nt * 16 + lm];
#pragma unroll
  for (int mt = 0; mt < 4; mt++) {
#pragma unroll
    for (int nt = 0; nt < 4; nt++) {
      const int row0 = m0 + wr * 64 + mt * 16 + lq * 4;
      const int col = n0 + wc * 64 + nt * 16 + lm;
#pragma unroll
      for (int r = 0; r < 4; r++)
        Y16[(size_t)(row0 + r) * 256 + col] = (ushortT)f2bf(acc[mt][nt][r] + biasv[nt]);
    }
  }
}

// --------------------- batched-MFMA LSTM recurrence (v3) --------------------
// Block = 512 thr = 8 waves, 16 batch rows. Text: 8 compute waves (16 gate
// cols each); A/V: waves 0-3 compute, all 8 stage/flush.
// Raw s_barrier with lgkmcnt-only drain (no vmcnt drain per step); xp loads
// issued 2 steps ahead, committed to LDS 1 step after issue (full-step slack).
__device__ __forceinline__ void bar_lgkm() {
  asm volatile("s_waitcnt lgkmcnt(0)" ::: "memory");
  __builtin_amdgcn_sched_barrier(0);
  __builtin_amdgcn_s_barrier();
  __builtin_amdgcn_sched_barrier(0);
}

template <int H, int COFF, int CW>
__device__ __forceinline__ void recur_impl3(const ushortT* __restrict__ xp,   // [B*T][4H]
                                            const ushortT* __restrict__ Whh, // [4H][H]
                                            ushortT* __restrict__ z,         // [B*T][256]
                                            int bblk, char* smem_) {
  constexpr int KC = H / 32;
  constexpr int C4H = 4 * H;
  constexpr int HP = H + 8;            // h-ring row stride
  constexpr int XP = C4H + 8;          // xp-stage row stride
  constexpr int RING = 6;
  constexpr int NCH4 = C4H / 256;      // uint4 per staging thread (512 thr)
  constexpr int CRB = H / 8;           // 16B runs per z row
  constexpr int FPT = (64 * CRB) / 512;  // flush uint4 per thread
  ushortT* hbuf = (ushortT*)smem_;                 // [RING][16][HP]
  ushortT* xps = hbuf + RING * 16 * HP;            // [2][16][XP]
  const int tid = threadIdx.x;
  const int s = tid >> 6, lane = tid & 63;
  const int lm = lane & 15, lq = lane >> 4;
  const int b0 = bblk * 16;
  const int srow = tid >> 5, sch = tid & 31;
  const ushortT* xrowp = xp + (size_t)(b0 + srow) * 256 * C4H + sch * (C4H / 32);
  ushortT* xdst0 = &xps[srow * XP + sch * (C4H / 32)];

  bf16x8 bw[4][KC];
  if (s < CW) {
#pragma unroll
    for (int g = 0; g < 4; g++)
#pragma unroll
      for (int kc = 0; kc < KC; kc++) {
        const int n = g * H + s * 16 + lm;
        bw[g][kc] = *(const bf16x8*)(Whh + (size_t)n * H + kc * 32 + lq * 8);
      }
  }
  for (int i = tid; i < 16 * HP; i += 512) hbuf[(RING - 1) * 16 * HP + i] = 0;

  uint4 svA[NCH4], svB[NCH4];
  {  // prologue: stage t=0 directly into xps[0]; issue loads for t=1 -> svB
    const uint4* s0 = (const uint4*)(xrowp);
#pragma unroll
    for (int i = 0; i < NCH4; i++) svA[i] = s0[i];
    uint4* d0 = (uint4*)xdst0;
#pragma unroll
    for (int i = 0; i < NCH4; i++) d0[i] = svA[i];
    const uint4* s1 = (const uint4*)(xrowp + (size_t)C4H);
#pragma unroll
    for (int i = 0; i < NCH4; i++) svB[i] = s1[i];
  }
  float cst[4] = {0.f, 0.f, 0.f, 0.f};
  __syncthreads();

  // step t: issue loads(t+2) -> svI; commit svC (data for t+1, issued at t-1)
  // into xps[(t+1)&1]; compute with xps[t&1]; lgkm-barrier.
  auto step = [&](int t, uint4 (&svI)[NCH4], uint4 (&svC)[NCH4]) {
    // ---- flush h-ring to z (4 rows, wide stores), off the critical path ----
    if (t >= 4 && (t & 3) == 0) {
      const int t0 = t - 4;
#pragma unroll
      for (int i = 0; i < FPT; i++) {
        const int q = i * 512 + tid;
        const int m = q / (4 * CRB), j = (q / CRB) & 3, cr = q % CRB;
        const uint4 v = *(const uint4*)&hbuf[((t0 + j) % RING) * 16 * HP + m * HP + cr * 8];
        *(uint4*)&z[((size_t)(b0 + m) * 256 + t0 + j) * 256 + COFF + cr * 8] = v;
      }
    }
    // ---- issue coalesced loads for step t+2 ----
    {
      const int tn = (t + 2 < 256) ? t + 2 : 255;
      const uint4* src = (const uint4*)(xrowp + (size_t)tn * C4H);
#pragma unroll
      for (int i = 0; i < NCH4; i++) svI[i] = src[i];
    }
    // ---- commit loads for t+1 (issued a full step ago -> no stall) ----
    {
      uint4* dst = (uint4*)(xdst0 + ((t + 1) & 1) * 16 * XP);
#pragma unroll
      for (int i = 0; i < NCH4; i++) dst[i] = svC[i];
    }
    if (s < CW) {
      // ---- gate GEMM ----
      const ushortT* hb = &hbuf[((t + RING - 1) % RING) * 16 * HP + lm * HP];
      bf16x8 af[KC];
#pragma unroll
      for (int kc = 0; kc < KC; kc++) af[kc] = *(const bf16x8*)(hb + kc * 32 + lq * 8);
      f32x4 acc[4];
#pragma unroll
      for (int g = 0; g < 4; g++) acc[g] = (f32x4){0.f, 0.f, 0.f, 0.f};
#pragma unroll
      for (int kc = 0; kc < KC; kc++)
#pragma unroll
        for (int g = 0; g < 4; g++)
          acc[g] = __builtin_amdgcn_mfma_f32_16x16x32_bf16(af[kc], bw[g][kc], acc[g], 0, 0, 0);
      // ---- activations (fused: 5 exp + 2 rcp per h) + h write ----
      const ushortT* xb = &xps[(t & 1) * 16 * XP];
      ushortT* hw = &hbuf[(t % RING) * 16 * HP];
      const int col = s * 16 + lm;
#pragma unroll
      for (int r = 0; r < 4; r++) {
        const int xrow = (lq * 4 + r) * XP;
        const float iv = acc[0][r] + bf2f(xb[xrow + 0 * H + col]);
        const float fv = acc[1][r] + bf2f(xb[xrow + 1 * H + col]);
        const float gg = acc[2][r] + bf2f(xb[xrow + 2 * H + col]);
        const float ov = acc[3][r] + bf2f(xb[xrow + 3 * H + col]);
        const float ei = __expf(-iv), ef = __expf(-fv), eg = __expf(-2.f * gg);
        const float pi = 1.f + ei, pf = 1.f + ef, pg = 1.f + eg;
        const float cc = (cst[r] * pi * pg + (1.f - eg) * pf) *
                         __builtin_amdgcn_rcpf(pf * pi * pg);
        cst[r] = cc;
        const float ec = __expf(-2.f * cc), eo = __expf(-ov);
        const float hv = (1.f - ec) * __builtin_amdgcn_rcpf((1.f + eo) * (1.f + ec));
        hw[(lq * 4 + r) * HP + col] = (ushortT)f2bf(hv);
      }
    }
    // ---- lgkm-only barrier: no per-step vmcnt drain ----
    bar_lgkm();
  };

  for (int t = 0; t < 256; t += 2) {
    step(t, svA, svB);
    step(t + 1, svB, svA);
  }
  // final flush: z rows 252..255
  {
    const int t0 = 252;
#pragma unroll
    for (int i = 0; i < FPT; i++) {
      const int q = i * 512 + tid;
      const int m = q / (4 * CRB), j = (q / CRB) & 3, cr = q % CRB;
      const uint4 v = *(const uint4*)&hbuf[((t0 + j) % RING) * 16 * HP + m * HP + cr * 8];
      *(uint4*)&z[((size_t)(b0 + m) * 256 + t0 + j) * 256 + COFF + cr * 8] = v;
    }
  }
}

__global__ __launch_bounds__(512, 1) void recur3_k(const ushortT* __restrict__ xpt,
                                                   const ushortT* __restrict__ xpa,
                                                   const ushortT* __restrict__ xpv_,
                                                   const ushortT* __restrict__ Wt,
                                                   const ushortT* __restrict__ Wa,
                                                   const ushortT* __restrict__ Wv,
                                                   ushortT* __restrict__ z) {
  extern __shared__ char smem[];
  const int bid = blockIdx.x;
  if (bid < 16) recur_impl3<128, 128, 8>(xpt, Wt, z, bid, smem);
  else if (bid < 32) recur_impl3<64, 0, 4>(xpa, Wa, z, bid - 16, smem);
  else recur_impl3<64, 64, 4>(xpv_, Wv, z, bid - 32, smem);
}

// ------------------------------- fusion ------------------------------------
__global__ __launch_bounds__(192) void fusion_k(const ushortT* __restrict__ z,
                                                const float* __restrict__ W1,
                                                const float* __restrict__ b1,
                                                const float* __restrict__ W2,
                                                const float* __restrict__ b2,
                                                const float* __restrict__ fw,
                                                float* __restrict__ s_acc,
                                                float* __restrict__ sumsq) {
  __shared__ __align__(16) float zs[256 * 36];
  __shared__ float red[8];
  const int tid = threadIdx.x;
  const int b = blockIdx.x >> 3;
  const int t0 = (blockIdx.x & 7) * 32;
  const ushortT* zb = z + (size_t)b * 65536;
  float sq = 0.0f;
  for (int idx = tid; idx < 33 * 256; idx += 192) {
    const int row = idx >> 8, k = idx & 255;
    int t = t0 + row; if (t >= 256) t -= 256;
    const float v = bf2f(zb[t * 256 + k]);
    zs[k * 36 + row] = v;
    if (row < 32) sq += v * v;
  }
  __syncthreads();
  const int dg = tid >> 3;
  const int rg = tid & 7;
  const float* w1p = W1 + dg * 256;
  const float* w2p = W2 + dg * 513;
  float aa[4] = {}, ab1[4] = {}, ab2[4] = {};
#pragma unroll 4
  for (int k = 0; k < 256; k++) {
    const float w1v = w1p[k];
    const float w21 = w2p[1 + k];
    const float w22 = w2p[257 + k];
    const float* zr = &zs[k * 36 + (rg << 2)];
    const float4 za = *(const float4*)zr;
    const float z4 = zr[4];
    aa[0]  += za.x * w1v; aa[1]  += za.y * w1v; aa[2]  += za.z * w1v; aa[3]  += za.w * w1v;
    ab1[0] += za.x * w21; ab1[1] += za.y * w21; ab1[2] += za.z * w21; ab1[3] += za.w * w21;
    ab2[0] += za.y * w22; ab2[1] += za.z * w22; ab2[2] += za.w * w22; ab2[3] += z4   * w22;
  }
  const float b1v = b1[dg];
  const float b2v = b2[dg] + w2p[0];
  const float fwv = fw[dg];
  float s = 0.0f;
#pragma unroll
  for (int i = 0; i < 4; i++) {
    const float a  = aa[i] + b1v;
    const float bb = ab1[i] + ab2[i] + b2v;
    s += a * bb;
  }
  s *= fwv;
#pragma unroll
  for (int off = 32; off > 0; off >>= 1) {
    s  += __shfl_down(s, off);
    sq += __shfl_down(sq, off);
  }
  const int wid = tid >> 6;
  if ((tid & 63) == 0) { red[wid * 2] = s; red[wid * 2 + 1] = sq; }
  __syncthreads();
  if (tid == 0) {
    atomicAdd(&s_acc[b], red[0] + red[2] + red[4]);
    atomicAdd(&sumsq[b], red[1] + red[3] + red[5]);
  }
}

// ------------------------------- epilogue ----------------------------------
__global__ __launch_bounds__(256) void final_k(const float* __restrict__ s_acc,
                                               const float* __restrict__ sumsq,
                                               float* __restrict__ out) {
  __shared__ float red[4];
  const int tid = threadIdx.x;
  out[tid] = s_acc[tid] * (1.0f / 256.0f);
  float sq = sqrtf(sumsq[tid]);
#pragma unroll
  for (int off = 32; off > 0; off >>= 1) sq += __shfl_down(sq, off);
  if ((tid & 63) == 0) red[tid >> 6] = sq;
  __syncthreads();
  if (tid == 0) out[256] = (red[0] + red[1] + red[2] + red[3]) * (1.0f / 256.0f);
}

// ---------------------------------------------------------------------------
extern "C" void kernel_launch(void* const* d_in, const int* in_sizes, int n_in,
                              void* d_out, int out_size, void* d_ws, size_t ws_size,
                              hipStream_t stream) {
  const float* text   = (const float*)d_in[0];
  const float* audio  = (const float*)d_in[1];
  const float* vision = (const float*)d_in[2];
  const float* Wih_t  = (const float*)d_in[3];
  const float* Whh_t  = (const float*)d_in[4];
  const float* b_t    = (const float*)d_in[5];
  const float* Wih_a  = (const float*)d_in[6];
  const float* Whh_a  = (const float*)d_in[7];
  const float* b_a    = (const float*)d_in[8];
  const float* Wih_v  = (const float*)d_in[9];
  const float* Whh_v  = (const float*)d_in[10];
  const float* b_v    = (const float*)d_in[11];
  const float* W1     = (const float*)d_in[12];
  const float* b1     = (const float*)d_in[13];
  const float* W2     = (const float*)d_in[14];
  const float* b2     = (const float*)d_in[15];
  const float* fw     = (const float*)d_in[16];

  // workspace layout (bf16 elems unless noted)
  ushortT* xpt = (ushortT*)d_ws;               // 65536*512
  ushortT* xpa = xpt + (size_t)33554432;       // 65536*256
  ushortT* xpv = xpa + (size_t)16777216;       // 65536*256
  ushortT* z16 = xpv + (size_t)16777216;       // 65536*256
  float* s_acc = (float*)(z16 + (size_t)16777216);  // 256 f32
  float* sumsq = s_acc + 256;                       // 256 f32
  ushortT* WhhT16 = (ushortT*)(sumsq + 256);   // 512*128
  ushortT* WhhA16 = WhhT16 + 65536;            // 256*64
  ushortT* WhhV16 = WhhA16 + 16384;            // 256*64
  // scratch aliased into z16 (fully consumed before recur3_k writes z):
  ushortT* A16a  = z16;                        // 65536*96
  ushortT* A16v  = A16a + (size_t)6291456;     // 65536*64
  ushortT* Wt768 = A16v + (size_t)4194304;     // 512*768
  ushortT* WA16  = Wt768 + 393216;             // 256*96
  ushortT* WV16  = WA16 + 24576;               // 256*64

  hipMemsetAsync(s_acc, 0, 512 * sizeof(float), stream);

  pad_cvt_k<768, 768><<<1536, 256, 0, stream>>>(Wih_t, Wt768, 512 * 768);
  pad_cvt_k<128, 128><<<256, 256, 0, stream>>>(Whh_t, WhhT16, 512 * 128);
  pad_cvt_k<64, 64><<<64, 256, 0, stream>>>(Whh_a, WhhA16, 256 * 64);
  pad_cvt_k<64, 64><<<64, 256, 0, stream>>>(Whh_v, WhhV16, 256 * 64);
  pad_cvt_k<96, 74><<<96, 256, 0, stream>>>(Wih_a, WA16, 256 * 96);
  pad_cvt_k<64, 35><<<64, 256, 0, stream>>>(Wih_v, WV16, 256 * 64);
  pad_cvt_k<96, 74><<<24576, 256, 0, stream>>>(audio, A16a, 65536 * 96);
  pad_cvt_k<64, 35><<<16384, 256, 0, stream>>>(vision, A16v, 65536 * 64);

  gemm_text2_k<<<1024, 512, 0, stream>>>(text, Wt768, b_t, xpt);
  gemm_xp_k<96><<<dim3(2, 512), 256, 0, stream>>>(A16a, WA16, b_a, xpa);
  gemm_xp_k<64><<<dim3(2, 512), 256, 0, stream>>>(A16v, WV16, b_v, xpv);
  // dynamic LDS: text variant needs 6*16*136*2 + 2*16*520*2 = 59392 B
  recur3_k<<<48, 512, 59392, stream>>>(xpt, xpa, xpv, WhhT16, WhhA16, WhhV16, z16);
  fusion_k<<<2048, 192, 0, stream>>>(z16, W1, b1, W2, b2, fw, s_acc, sumsq);
  final_k<<<1, 256, 0, stream>>>(s_acc, sumsq, (float*)d_out);
}

// Round 4
// 846.456 us; speedup vs baseline: 1.1340x; 1.0933x over previous
//
#include <hip/hip_runtime.h>
#include <math.h>

// ---------------------------------------------------------------------------
// B=256, T=256, LEN=256 (audio 64 | vision 64 | text 128), RANK=24, EXT=513
// xp gate tensors are stored in a recurrence-native layout:
//   chunk(bblk,t) = CW*64 threads * 16 ushorts, split in two gate-banks:
//   addr = ((bblk*256+t)*TS) + (g>>1)*(TS/2) + tid*8 + (g&1)*4 + rr
//   where tid = cs*64 + mq*16 + clm  (cs=col>>4 within gate, mq=batch>>2,
//   clm=col&15, rr=batch&3), TS = CW*64*16.
// ---------------------------------------------------------------------------

typedef unsigned short ushortT;
typedef short bf16x8 __attribute__((ext_vector_type(8)));
typedef float f32x4 __attribute__((ext_vector_type(4)));

__device__ __forceinline__ unsigned int f2bf(float f) {  // RNE to bf16
  unsigned int u = __float_as_uint(f);
  u += 0x7FFFu + ((u >> 16) & 1u);
  return u >> 16;
}
__device__ __forceinline__ unsigned int pk2bf(float lo, float hi) {
  return f2bf(lo) | (f2bf(hi) << 16);
}
__device__ __forceinline__ float bf2f(ushortT u) {
  return __uint_as_float(((unsigned int)u) << 16);
}

// ------------------ generic fp32 -> bf16 convert (+K-pad) -------------------
template <int KP, int KIN>
__global__ __launch_bounds__(256) void pad_cvt_k(const float* __restrict__ src,
                                                 ushortT* __restrict__ dst, int total) {
  const int i = blockIdx.x * 256 + threadIdx.x;
  if (i >= total) return;
  if constexpr (KP == KIN) {
    dst[i] = (ushortT)f2bf(src[i]);
  } else {
    const int row = i / KP, c = i - row * KP;
    dst[i] = (c < KIN) ? (ushortT)f2bf(src[(size_t)row * KIN + c]) : (ushortT)0;
  }
}

// ---------------- text input projection GEMM (bf16 MFMA, 128x256) -----------
// Computes bf16( X[M,768] @ W16[512,768]^T + bias ), stores into the
// recurrence-native xp layout (TS=8192, CW*64=512 threads, gate size 128).
#define SA2 40  // LDS row stride (BK=32 + 8 pad)
__global__ __launch_bounds__(512) void gemm_text2_k(const float* __restrict__ X,
                                                    const ushortT* __restrict__ W16,
                                                    const float* __restrict__ bias,
                                                    ushortT* __restrict__ Y16) {
  const int K = 768;
  __shared__ __align__(16) ushortT As[128 * SA2];
  __shared__ __align__(16) ushortT Bs[256 * SA2];
  const unsigned int lin = blockIdx.x;
  const int gb = (int)(lin >> 4), rb = (int)(lin & 15);
  const int m0 = (gb * 8 + (rb & 7)) * 128;
  const int n0 = (rb >> 3) * 256;
  const int tid = threadIdx.x;
  const int wave = tid >> 6, lane = tid & 63;
  const int wr = wave >> 2, wc = wave & 3;          // 2x4 wave grid (64x64 each)
  const int lm = lane & 15, lq = lane >> 4;
  const int arow = tid >> 2, aq = (tid & 3) * 8;    // A staging: 8 fp32/thread
  const int brow = tid >> 1, bq = (tid & 1) * 16;   // B staging: 16 bf16/thread

  const float*   Xp = X + (size_t)(m0 + arow) * K + aq;
  const ushortT* Wp = W16 + (size_t)(n0 + brow) * K + bq;
  uint4* As_w = (uint4*)&As[arow * SA2 + aq];
  uint4* Bs_w = (uint4*)&Bs[brow * SA2 + bq];

  f32x4 acc[4][4];
#pragma unroll
  for (int i = 0; i < 4; i++)
#pragma unroll
    for (int j = 0; j < 4; j++) acc[i][j] = (f32x4){0.f, 0.f, 0.f, 0.f};

  for (int k0 = 0; k0 < K; k0 += 32) {
    const float4 a0 = *(const float4*)(Xp + k0);
    const float4 a1 = *(const float4*)(Xp + k0 + 4);
    const uint4 b0v = *(const uint4*)(Wp + k0);
    const uint4 b1v = *(const uint4*)(Wp + k0 + 8);
    __syncthreads();
    uint4 ao;
    ao.x = pk2bf(a0.x, a0.y); ao.y = pk2bf(a0.z, a0.w);
    ao.z = pk2bf(a1.x, a1.y); ao.w = pk2bf(a1.z, a1.w);
    As_w[0] = ao;
    Bs_w[0] = b0v;
    Bs_w[1] = b1v;
    __syncthreads();
    bf16x8 af[4], bfv[4];
#pragma unroll
    for (int mt = 0; mt < 4; mt++)
      af[mt] = *(const bf16x8*)&As[(wr * 64 + mt * 16 + lm) * SA2 + lq * 8];
#pragma unroll
    for (int nt = 0; nt < 4; nt++)
      bfv[nt] = *(const bf16x8*)&Bs[(wc * 64 + nt * 16 + lm) * SA2 + lq * 8];
#pragma unroll
    for (int mt = 0; mt < 4; mt++)
#pragma unroll
      for (int nt = 0; nt < 4; nt++)
        acc[mt][nt] = __builtin_amdgcn_mfma_f32_16x16x32_bf16(af[mt], bfv[nt], acc[mt][nt], 0, 0, 0);
  }
  float biasv[4];
#pragma unroll
  for (int nt = 0; nt < 4; nt++) biasv[nt] = bias[n0 + wc * 64 + nt * 16 + lm];
  // ---- scatter store into recurrence-native layout (TS=8192, gate=128) ----
  const int bb = m0 >> 8;                     // batch index (const per block)
  const int mq16 = ((bb & 15) >> 2) * 16;
  const int mr2 = bb & 3;
  const size_t chunk0 = (size_t)((bb >> 4) * 256) * 8192;
  const int tbase = (m0 & 255) + wr * 64 + lq * 4;   // t of acc row r=0
#pragma unroll
  for (int nt = 0; nt < 4; nt++) {
    const int C = n0 + wc * 64 + nt * 16 + lm;       // gate-major col
    const int g = C >> 7, cc = C & 127;
    const int off_nt = (g >> 1) * 4096 + ((cc >> 4) * 64 + mq16 + (cc & 15)) * 8 +
                       (g & 1) * 4 + mr2;
#pragma unroll
    for (int mt = 0; mt < 4; mt++) {
      const size_t a0 = chunk0 + (size_t)(tbase + mt * 16) * 8192 + off_nt;
#pragma unroll
      for (int r = 0; r < 4; r++)
        Y16[a0 + (size_t)r * 8192] = (ushortT)f2bf(acc[mt][nt][r] + biasv[nt]);
    }
  }
}

// ------------- audio/vision input projection (small-K bf16 MFMA) ------------
// Stores into recurrence-native xp layout (TS=4096, CW*64=256 threads, gate=64).
template <int KP>
__global__ __launch_bounds__(256) void gemm_xp_k(const ushortT* __restrict__ A16,
                                                 const ushortT* __restrict__ B16,
                                                 const float* __restrict__ bias,
                                                 ushortT* __restrict__ Y16) {
  constexpr int SB = KP + 8;
  __shared__ __align__(16) ushortT As[128 * SB];
  __shared__ __align__(16) ushortT Bs[128 * SB];
  const int n0 = blockIdx.x * 128;
  const int m0 = blockIdx.y * 128;
  const int tid = threadIdx.x;
  const int srow = tid >> 1, shalf = tid & 1;
  const int wave = tid >> 6, lane = tid & 63;
  const int wr = wave >> 1, wc = wave & 1;
  const int lm = lane & 15, lq = lane >> 4;

  const uint4* ap = (const uint4*)(A16 + (size_t)(m0 + srow) * KP + shalf * (KP / 2));
  const uint4* bp = (const uint4*)(B16 + (size_t)(n0 + srow) * KP + shalf * (KP / 2));
  uint4* aw = (uint4*)&As[srow * SB + shalf * (KP / 2)];
  uint4* bw = (uint4*)&Bs[srow * SB + shalf * (KP / 2)];
#pragma unroll
  for (int i = 0; i < KP / 16; i++) { aw[i] = ap[i]; bw[i] = bp[i]; }
  __syncthreads();

  constexpr int KC = KP / 32;
  f32x4 acc[4][4];
#pragma unroll
  for (int i = 0; i < 4; i++)
#pragma unroll
    for (int j = 0; j < 4; j++) acc[i][j] = (f32x4){0.f, 0.f, 0.f, 0.f};
#pragma unroll
  for (int ks = 0; ks < KC; ks++) {
    bf16x8 af[4], bfv[4];
#pragma unroll
    for (int mt = 0; mt < 4; mt++)
      af[mt] = *(const bf16x8*)&As[(wr * 64 + mt * 16 + lm) * SB + ks * 32 + lq * 8];
#pragma unroll
    for (int nt = 0; nt < 4; nt++)
      bfv[nt] = *(const bf16x8*)&Bs[(wc * 64 + nt * 16 + lm) * SB + ks * 32 + lq * 8];
#pragma unroll
    for (int mt = 0; mt < 4; mt++)
#pragma unroll
      for (int nt = 0; nt < 4; nt++)
        acc[mt][nt] = __builtin_amdgcn_mfma_f32_16x16x32_bf16(af[mt], bfv[nt], acc[mt][nt], 0, 0, 0);
  }
  float biasv[4];
#pragma unroll
  for (int nt = 0; nt < 4; nt++) biasv[nt] = bias[n0 + wc * 64 + nt * 16 + lm];
  // ---- scatter store into recurrence-native layout (TS=4096, gate=64) ----
  const int bb = m0 >> 8;
  const int mq16 = ((bb & 15) >> 2) * 16;
  const int mr2 = bb & 3;
  const size_t chunk0 = (size_t)((bb >> 4) * 256) * 4096;
  const int tbase = (m0 & 255) + wr * 64 + lq * 4;
#pragma unroll
  for (int nt = 0; nt < 4; nt++) {
    const int C = n0 + wc * 64 + nt * 16 + lm;
    const int g = C >> 6, cc = C & 63;
    const int off_nt = (g >> 1) * 2048 + ((cc >> 4) * 64 + mq16 + (cc & 15)) * 8 +
                       (g & 1) * 4 + mr2;
#pragma unroll
    for (int mt = 0; mt < 4; mt++) {
      const size_t a0 = chunk0 + (size_t)(tbase + mt * 16) * 4096 + off_nt;
#pragma unroll
      for (int r = 0; r < 4; r++)
        Y16[a0 + (size_t)r * 4096] = (ushortT)f2bf(acc[mt][nt][r] + biasv[nt]);
    }
  }
}

// --------------------- batched-MFMA LSTM recurrence (v4) --------------------
// Gate addends live in registers: 2 coalesced dwordx4 loads per compute
// thread per step from the recurrence-native xp layout, prefetched ~2 steps
// ahead. No xp LDS staging at all; LDS holds only the h-ring.
__device__ __forceinline__ void bar_lgkm() {
  asm volatile("s_waitcnt lgkmcnt(0)" ::: "memory");
  __builtin_amdgcn_sched_barrier(0);
  __builtin_amdgcn_s_barrier();
  __builtin_amdgcn_sched_barrier(0);
}

template <int H, int COFF, int CW>
__device__ __forceinline__ void recur_impl4(const ushortT* __restrict__ xp,   // native layout
                                            const ushortT* __restrict__ Whh, // [4H][H]
                                            ushortT* __restrict__ z,         // [B*T][256]
                                            int bblk, char* smem_) {
  constexpr int KC = H / 32;
  constexpr int HP = H + 8;              // h-ring row stride
  constexpr int RING = 6;
  constexpr int CRB = H / 8;             // 16B runs per z row
  constexpr int FPT = (64 * CRB) / 512;  // flush uint4 per thread
  constexpr int TS = CW * 64 * 16;       // ushorts per t-chunk
  ushortT* hbuf = (ushortT*)smem_;       // [RING][16][HP]
  const int tid = threadIdx.x;
  const int s = tid >> 6, lane = tid & 63;
  const int lm = lane & 15, lq = lane >> 4;
  const int b0 = bblk * 16;
  const bool comp = (s < CW);
  const ushortT* xg = xp + (size_t)(bblk * 256) * TS + tid * 8;

  bf16x8 bw[4][KC];
  if (comp) {
#pragma unroll
    for (int g = 0; g < 4; g++)
#pragma unroll
      for (int kc = 0; kc < KC; kc++) {
        const int n = g * H + s * 16 + lm;
        bw[g][kc] = *(const bf16x8*)(Whh + (size_t)n * H + kc * 32 + lq * 8);
      }
  }
  for (int i = tid; i < 16 * HP; i += 512) hbuf[(RING - 1) * 16 * HP + i] = 0;

  uint4 gA[2], gB[2];
  if (comp) {
    gA[0] = *(const uint4*)(xg);
    gA[1] = *(const uint4*)(xg + TS / 2);
    gB[0] = *(const uint4*)(xg + TS);
    gB[1] = *(const uint4*)(xg + TS + TS / 2);
  }
  float cst[4] = {0.f, 0.f, 0.f, 0.f};
  __syncthreads();

  // step t: extract gate addends from gCur; immediately re-issue loads for
  // t+2 into gCur (~2 steps of slack); MFMA; activations; lgkm-only barrier.
  auto step = [&](int t, uint4 (&gCur)[2]) {
    // ---- flush h-ring to z (4 rows, wide stores), off the critical path ----
    if (t >= 4 && (t & 3) == 0) {
      const int t0 = t - 4;
#pragma unroll
      for (int i = 0; i < FPT; i++) {
        const int q = i * 512 + tid;
        const int m = q / (4 * CRB), j = (q / CRB) & 3, cr = q % CRB;
        const uint4 v = *(const uint4*)&hbuf[((t0 + j) % RING) * 16 * HP + m * HP + cr * 8];
        *(uint4*)&z[((size_t)(b0 + m) * 256 + t0 + j) * 256 + COFF + cr * 8] = v;
      }
    }
    if (comp) {
      // ---- extract 16 gate addends, then re-issue loads for t+2 ----
      unsigned int w[8] = {gCur[0].x, gCur[0].y, gCur[0].z, gCur[0].w,
                           gCur[1].x, gCur[1].y, gCur[1].z, gCur[1].w};
      float ad[4][4];
#pragma unroll
      for (int g = 0; g < 4; g++)
#pragma unroll
        for (int r = 0; r < 4; r++) {
          const unsigned int ww = w[g * 2 + (r >> 1)];
          ad[g][r] = __uint_as_float((r & 1) ? (ww & 0xffff0000u) : (ww << 16));
        }
      const int tn = (t + 2 < 256) ? t + 2 : 255;
      gCur[0] = *(const uint4*)(xg + (size_t)tn * TS);
      gCur[1] = *(const uint4*)(xg + (size_t)tn * TS + TS / 2);
      // ---- gate GEMM ----
      const ushortT* hb = &hbuf[((t + RING - 1) % RING) * 16 * HP + lm * HP];
      bf16x8 af[KC];
#pragma unroll
      for (int kc = 0; kc < KC; kc++) af[kc] = *(const bf16x8*)(hb + kc * 32 + lq * 8);
      f32x4 acc[4];
#pragma unroll
      for (int g = 0; g < 4; g++) acc[g] = (f32x4){0.f, 0.f, 0.f, 0.f};
#pragma unroll
      for (int kc = 0; kc < KC; kc++)
#pragma unroll
        for (int g = 0; g < 4; g++)
          acc[g] = __builtin_amdgcn_mfma_f32_16x16x32_bf16(af[kc], bw[g][kc], acc[g], 0, 0, 0);
      // ---- activations (fused: 5 exp + 2 rcp per h) + h write ----
      ushortT* hw = &hbuf[(t % RING) * 16 * HP];
      const int col = s * 16 + lm;
#pragma unroll
      for (int r = 0; r < 4; r++) {
        const float iv = acc[0][r] + ad[0][r];
        const float fv = acc[1][r] + ad[1][r];
        const float gg = acc[2][r] + ad[2][r];
        const float ov = acc[3][r] + ad[3][r];
        const float ei = __expf(-iv), ef = __expf(-fv), eg = __expf(-2.f * gg);
        const float pi = 1.f + ei, pf = 1.f + ef, pg = 1.f + eg;
        const float cc = (cst[r] * pi * pg + (1.f - eg) * pf) *
                         __builtin_amdgcn_rcpf(pf * pi * pg);
        cst[r] = cc;
        const float ec = __expf(-2.f * cc), eo = __expf(-ov);
        const float hv = (1.f - ec) * __builtin_amdgcn_rcpf((1.f + eo) * (1.f + ec));
        hw[(lq * 4 + r) * HP + col] = (ushortT)f2bf(hv);
      }
    }
    // ---- lgkm-only barrier: no per-step vmcnt drain ----
    bar_lgkm();
  };

  for (int t = 0; t < 256; t += 2) {
    step(t, gA);
    step(t + 1, gB);
  }
  // final flush: z rows 252..255
  {
    const int t0 = 252;
#pragma unroll
    for (int i = 0; i < FPT; i++) {
      const int q = i * 512 + tid;
      const int m = q / (4 * CRB), j = (q / CRB) & 3, cr = q % CRB;
      const uint4 v = *(const uint4*)&hbuf[((t0 + j) % RING) * 16 * HP + m * HP + cr * 8];
      *(uint4*)&z[((size_t)(b0 + m) * 256 + t0 + j) * 256 + COFF + cr * 8] = v;
    }
  }
}

__global__ __launch_bounds__(512, 1) void recur4_k(const ushortT* __restrict__ xpt,
                                                   const ushortT* __restrict__ xpa,
                                                   const ushortT* __restrict__ xpv_,
                                                   const ushortT* __restrict__ Wt,
                                                   const ushortT* __restrict__ Wa,
                                                   const ushortT* __restrict__ Wv,
                                                   ushortT* __restrict__ z) {
  extern __shared__ char smem[];
  const int bid = blockIdx.x;
  if (bid < 16) recur_impl4<128, 128, 8>(xpt, Wt, z, bid, smem);
  else if (bid < 32) recur_impl4<64, 0, 4>(xpa, Wa, z, bid - 16, smem);
  else recur_impl4<64, 64, 4>(xpv_, Wv, z, bid - 32, smem);
}

// ------------------------------- fusion ------------------------------------
__global__ __launch_bounds__(192) void fusion_k(const ushortT* __restrict__ z,
                                                const float* __restrict__ W1,
                                                const float* __restrict__ b1,
                                                const float* __restrict__ W2,
                                                const float* __restrict__ b2,
                                                const float* __restrict__ fw,
                                                float* __restrict__ s_acc,
                                                float* __restrict__ sumsq) {
  __shared__ __align__(16) float zs[256 * 36];
  __shared__ float red[8];
  const int tid = threadIdx.x;
  const int b = blockIdx.x >> 3;
  const int t0 = (blockIdx.x & 7) * 32;
  const ushortT* zb = z + (size_t)b * 65536;
  float sq = 0.0f;
  for (int idx = tid; idx < 33 * 256; idx += 192) {
    const int row = idx >> 8, k = idx & 255;
    int t = t0 + row; if (t >= 256) t -= 256;
    const float v = bf2f(zb[t * 256 + k]);
    zs[k * 36 + row] = v;
    if (row < 32) sq += v * v;
  }
  __syncthreads();
  const int dg = tid >> 3;
  const int rg = tid & 7;
  const float* w1p = W1 + dg * 256;
  const float* w2p = W2 + dg * 513;
  float aa[4] = {}, ab1[4] = {}, ab2[4] = {};
#pragma unroll 4
  for (int k = 0; k < 256; k++) {
    const float w1v = w1p[k];
    const float w21 = w2p[1 + k];
    const float w22 = w2p[257 + k];
    const float* zr = &zs[k * 36 + (rg << 2)];
    const float4 za = *(const float4*)zr;
    const float z4 = zr[4];
    aa[0]  += za.x * w1v; aa[1]  += za.y * w1v; aa[2]  += za.z * w1v; aa[3]  += za.w * w1v;
    ab1[0] += za.x * w21; ab1[1] += za.y * w21; ab1[2] += za.z * w21; ab1[3] += za.w * w21;
    ab2[0] += za.y * w22; ab2[1] += za.z * w22; ab2[2] += za.w * w22; ab2[3] += z4   * w22;
  }
  const float b1v = b1[dg];
  const float b2v = b2[dg] + w2p[0];
  const float fwv = fw[dg];
  float s = 0.0f;
#pragma unroll
  for (int i = 0; i < 4; i++) {
    const float a  = aa[i] + b1v;
    const float bb = ab1[i] + ab2[i] + b2v;
    s += a * bb;
  }
  s *= fwv;
#pragma unroll
  for (int off = 32; off > 0; off >>= 1) {
    s  += __shfl_down(s, off);
    sq += __shfl_down(sq, off);
  }
  const int wid = tid >> 6;
  if ((tid & 63) == 0) { red[wid * 2] = s; red[wid * 2 + 1] = sq; }
  __syncthreads();
  if (tid == 0) {
    atomicAdd(&s_acc[b], red[0] + red[2] + red[4]);
    atomicAdd(&sumsq[b], red[1] + red[3] + red[5]);
  }
}

// ------------------------------- epilogue ----------------------------------
__global__ __launch_bounds__(256) void final_k(const float* __restrict__ s_acc,
                                               const float* __restrict__ sumsq,
                                               float* __restrict__ out) {
  __shared__ float red[4];
  const int tid = threadIdx.x;
  out[tid] = s_acc[tid] * (1.0f / 256.0f);
  float sq = sqrtf(sumsq[tid]);
#pragma unroll
  for (int off = 32; off > 0; off >>= 1) sq += __shfl_down(sq, off);
  if ((tid & 63) == 0) red[tid >> 6] = sq;
  __syncthreads();
  if (tid == 0) out[256] = (red[0] + red[1] + red[2] + red[3]) * (1.0f / 256.0f);
}

// ---------------------------------------------------------------------------
extern "C" void kernel_launch(void* const* d_in, const int* in_sizes, int n_in,
                              void* d_out, int out_size, void* d_ws, size_t ws_size,
                              hipStream_t stream) {
  const float* text   = (const float*)d_in[0];
  const float* audio  = (const float*)d_in[1];
  const float* vision = (const float*)d_in[2];
  const float* Wih_t  = (const float*)d_in[3];
  const float* Whh_t  = (const float*)d_in[4];
  const float* b_t    = (const float*)d_in[5];
  const float* Wih_a  = (const float*)d_in[6];
  const float* Whh_a  = (const float*)d_in[7];
  const float* b_a    = (const float*)d_in[8];
  const float* Wih_v  = (const float*)d_in[9];
  const float* Whh_v  = (const float*)d_in[10];
  const float* b_v    = (const float*)d_in[11];
  const float* W1     = (const float*)d_in[12];
  const float* b1     = (const float*)d_in[13];
  const float* W2     = (const float*)d_in[14];
  const float* b2     = (const float*)d_in[15];
  const float* fw     = (const float*)d_in[16];

  // workspace layout (bf16 elems unless noted)
  ushortT* xpt = (ushortT*)d_ws;               // 65536*512 (native layout)
  ushortT* xpa = xpt + (size_t)33554432;       // 65536*256 (native layout)
  ushortT* xpv = xpa + (size_t)16777216;       // 65536*256 (native layout)
  ushortT* z16 = xpv + (size_t)16777216;       // 65536*256
  float* s_acc = (float*)(z16 + (size_t)16777216);  // 256 f32
  float* sumsq = s_acc + 256;                       // 256 f32
  ushortT* WhhT16 = (ushortT*)(sumsq + 256);   // 512*128
  ushortT* WhhA16 = WhhT16 + 65536;            // 256*64
  ushortT* WhhV16 = WhhA16 + 16384;            // 256*64
  // scratch aliased into z16 (fully consumed before recur4_k writes z):
  ushortT* A16a  = z16;                        // 65536*96
  ushortT* A16v  = A16a + (size_t)6291456;     // 65536*64
  ushortT* Wt768 = A16v + (size_t)4194304;     // 512*768
  ushortT* WA16  = Wt768 + 393216;             // 256*96
  ushortT* WV16  = WA16 + 24576;               // 256*64

  hipMemsetAsync(s_acc, 0, 512 * sizeof(float), stream);

  pad_cvt_k<768, 768><<<1536, 256, 0, stream>>>(Wih_t, Wt768, 512 * 768);
  pad_cvt_k<128, 128><<<256, 256, 0, stream>>>(Whh_t, WhhT16, 512 * 128);
  pad_cvt_k<64, 64><<<64, 256, 0, stream>>>(Whh_a, WhhA16, 256 * 64);
  pad_cvt_k<64, 64><<<64, 256, 0, stream>>>(Whh_v, WhhV16, 256 * 64);
  pad_cvt_k<96, 74><<<96, 256, 0, stream>>>(Wih_a, WA16, 256 * 96);
  pad_cvt_k<64, 35><<<64, 256, 0, stream>>>(Wih_v, WV16, 256 * 64);
  pad_cvt_k<96, 74><<<24576, 256, 0, stream>>>(audio, A16a, 65536 * 96);
  pad_cvt_k<64, 35><<<16384, 256, 0, stream>>>(vision, A16v, 65536 * 64);

  gemm_text2_k<<<1024, 512, 0, stream>>>(text, Wt768, b_t, xpt);
  gemm_xp_k<96><<<dim3(2, 512), 256, 0, stream>>>(A16a, WA16, b_a, xpa);
  gemm_xp_k<64><<<dim3(2, 512), 256, 0, stream>>>(A16v, WV16, b_v, xpv);
  // dynamic LDS: h-ring only; text variant needs 6*16*136*2 = 26112 B
  recur4_k<<<48, 512, 26112, stream>>>(xpt, xpa, xpv, WhhT16, WhhA16, WhhV16, z16);
  fusion_k<<<2048, 192, 0, stream>>>(z16, W1, b1, W2, b2, fw, s_acc, sumsq);
  final_k<<<1, 256, 0, stream>>>(s_acc, sumsq, (float*)d_out);
}

// Round 5
// 765.145 us; speedup vs baseline: 1.2545x; 1.1063x over previous
//
#include <hip/hip_runtime.h>
#include <math.h>

// ---------------------------------------------------------------------------
// B=256, T=256, LEN=256 (audio 64 | vision 64 | text 128), RANK=24, EXT=513
// xp gate tensors: [b][t][col][gate] (gate innermost, 4 ushorts = 8B per
// (b,t,col)). Achieved by permuting Wih rows as n' = col*4 + gate, so the
// GEMM's dense epilogue Y[row*4H + n'] directly produces this layout.
// ---------------------------------------------------------------------------

typedef unsigned short ushortT;
typedef short bf16x8 __attribute__((ext_vector_type(8)));
typedef float f32x4 __attribute__((ext_vector_type(4)));

__device__ __forceinline__ unsigned int f2bf(float f) {  // RNE to bf16
  unsigned int u = __float_as_uint(f);
  u += 0x7FFFu + ((u >> 16) & 1u);
  return u >> 16;
}
__device__ __forceinline__ unsigned int pk2bf(float lo, float hi) {
  return f2bf(lo) | (f2bf(hi) << 16);
}
__device__ __forceinline__ float bf2f(ushortT u) {
  return __uint_as_float(((unsigned int)u) << 16);
}

// ------------------- unified prep: fp32->bf16 cvt (+pad, +row-perm) ---------
// HR=0: plain; HR=H: dst row n' <- src row (n'&3)*H + (n'>>2)  (gate-major ->
// gate-innermost reorder of Wih rows).
template <int KP, int KIN, int HR>
__device__ __forceinline__ void cvt_range(const float* __restrict__ src,
                                          ushortT* __restrict__ dst,
                                          int i, int total) {
  if (i >= total) return;
  if constexpr (HR == 0 && KP == KIN) {
    dst[i] = (ushortT)f2bf(src[i]);
  } else {
    const int row = i / KP, c = i - row * KP;
    const int srow = HR ? ((row & 3) * HR + (row >> 2)) : row;
    const float v = (c < KIN) ? src[(size_t)srow * KIN + c] : 0.f;
    dst[i] = (ushortT)f2bf(v);
  }
}

__global__ __launch_bounds__(256) void prep_k(
    const float* __restrict__ Wih_t, const float* __restrict__ Whh_t,
    const float* __restrict__ Wih_a, const float* __restrict__ Whh_a,
    const float* __restrict__ Wih_v, const float* __restrict__ Whh_v,
    const float* __restrict__ audio, const float* __restrict__ vision,
    ushortT* __restrict__ Wt768, ushortT* __restrict__ WhhT16,
    ushortT* __restrict__ WA16, ushortT* __restrict__ WhhA16,
    ushortT* __restrict__ WV16, ushortT* __restrict__ WhhV16,
    ushortT* __restrict__ A16a, ushortT* __restrict__ A16v) {
  const int b = blockIdx.x, tid = threadIdx.x;
  if (b < 1536)       cvt_range<768, 768, 128>(Wih_t, Wt768, b * 256 + tid, 393216);
  else if (b < 1792)  cvt_range<128, 128, 0>(Whh_t, WhhT16, (b - 1536) * 256 + tid, 65536);
  else if (b < 1856)  cvt_range<64, 64, 0>(Whh_a, WhhA16, (b - 1792) * 256 + tid, 16384);
  else if (b < 1920)  cvt_range<64, 64, 0>(Whh_v, WhhV16, (b - 1856) * 256 + tid, 16384);
  else if (b < 2016)  cvt_range<96, 74, 64>(Wih_a, WA16, (b - 1920) * 256 + tid, 24576);
  else if (b < 2080)  cvt_range<64, 35, 64>(Wih_v, WV16, (b - 2016) * 256 + tid, 16384);
  else if (b < 26656) cvt_range<96, 74, 0>(audio, A16a, (b - 2080) * 256 + tid, 6291456);
  else                cvt_range<64, 35, 0>(vision, A16v, (b - 26656) * 256 + tid, 4194304);
}

// ---------------- text input projection GEMM (bf16 MFMA, 128x256) -----------
// Y16[M=65536, 512] = bf16( X[M,768] @ W16[512,768]^T + bias[perm] ); W16 rows
// pre-permuted gate-innermost, so the dense store IS the xp native layout.
#define SA2 40  // LDS row stride (BK=32 + 8 pad)
__global__ __launch_bounds__(512) void gemm_text2_k(const float* __restrict__ X,
                                                    const ushortT* __restrict__ W16,
                                                    const float* __restrict__ bias,
                                                    ushortT* __restrict__ Y16) {
  const int K = 768, N = 512;
  __shared__ __align__(16) ushortT As[128 * SA2];
  __shared__ __align__(16) ushortT Bs[256 * SA2];
  // n-siblings (same m-tile) at dispatch stride 8 -> same XCD -> A L2 reuse.
  const unsigned int lin = blockIdx.x;
  const int gb = (int)(lin >> 4), rb = (int)(lin & 15);
  const int m0 = (gb * 8 + (rb & 7)) * 128;
  const int n0 = (rb >> 3) * 256;
  const int tid = threadIdx.x;
  const int wave = tid >> 6, lane = tid & 63;
  const int wr = wave >> 2, wc = wave & 3;          // 2x4 wave grid (64x64 each)
  const int lm = lane & 15, lq = lane >> 4;
  const int arow = tid >> 2, aq = (tid & 3) * 8;    // A staging: 8 fp32/thread
  const int brow = tid >> 1, bq = (tid & 1) * 16;   // B staging: 16 bf16/thread

  const float*   Xp = X + (size_t)(m0 + arow) * K + aq;
  const ushortT* Wp = W16 + (size_t)(n0 + brow) * K + bq;
  uint4* As_w = (uint4*)&As[arow * SA2 + aq];
  uint4* Bs_w = (uint4*)&Bs[brow * SA2 + bq];

  f32x4 acc[4][4];
#pragma unroll
  for (int i = 0; i < 4; i++)
#pragma unroll
    for (int j = 0; j < 4; j++) acc[i][j] = (f32x4){0.f, 0.f, 0.f, 0.f};

  for (int k0 = 0; k0 < K; k0 += 32) {
    const float4 a0 = *(const float4*)(Xp + k0);
    const float4 a1 = *(const float4*)(Xp + k0 + 4);
    const uint4 b0v = *(const uint4*)(Wp + k0);
    const uint4 b1v = *(const uint4*)(Wp + k0 + 8);
    __syncthreads();
    uint4 ao;
    ao.x = pk2bf(a0.x, a0.y); ao.y = pk2bf(a0.z, a0.w);
    ao.z = pk2bf(a1.x, a1.y); ao.w = pk2bf(a1.z, a1.w);
    As_w[0] = ao;
    Bs_w[0] = b0v;
    Bs_w[1] = b1v;
    __syncthreads();
    bf16x8 af[4], bfv[4];
#pragma unroll
    for (int mt = 0; mt < 4; mt++)
      af[mt] = *(const bf16x8*)&As[(wr * 64 + mt * 16 + lm) * SA2 + lq * 8];
#pragma unroll
    for (int nt = 0; nt < 4; nt++)
      bfv[nt] = *(const bf16x8*)&Bs[(wc * 64 + nt * 16 + lm) * SA2 + lq * 8];
#pragma unroll
    for (int mt = 0; mt < 4; mt++)
#pragma unroll
      for (int nt = 0; nt < 4; nt++)
        acc[mt][nt] = __builtin_amdgcn_mfma_f32_16x16x32_bf16(af[mt], bfv[nt], acc[mt][nt], 0, 0, 0);
  }
  float biasv[4];
#pragma unroll
  for (int nt = 0; nt < 4; nt++) {
    const int C = n0 + wc * 64 + nt * 16 + lm;       // permuted col
    biasv[nt] = bias[((C & 3) << 7) + (C >> 2)];     // original gate-major idx
  }
#pragma unroll
  for (int mt = 0; mt < 4; mt++) {
#pragma unroll
    for (int nt = 0; nt < 4; nt++) {
      const int row0 = m0 + wr * 64 + mt * 16 + lq * 4;
      const int col = n0 + wc * 64 + nt * 16 + lm;
#pragma unroll
      for (int r = 0; r < 4; r++)
        Y16[(size_t)(row0 + r) * N + col] = (ushortT)f2bf(acc[mt][nt][r] + biasv[nt]);
    }
  }
}

// ------------- audio/vision input projection (small-K bf16 MFMA) ------------
template <int KP, int LOG2H>
__global__ __launch_bounds__(256) void gemm_xp_k(const ushortT* __restrict__ A16,
                                                 const ushortT* __restrict__ B16,
                                                 const float* __restrict__ bias,
                                                 ushortT* __restrict__ Y16) {
  constexpr int SB = KP + 8;
  __shared__ __align__(16) ushortT As[128 * SB];
  __shared__ __align__(16) ushortT Bs[128 * SB];
  const int n0 = blockIdx.x * 128;
  const int m0 = blockIdx.y * 128;
  const int tid = threadIdx.x;
  const int srow = tid >> 1, shalf = tid & 1;
  const int wave = tid >> 6, lane = tid & 63;
  const int wr = wave >> 1, wc = wave & 1;
  const int lm = lane & 15, lq = lane >> 4;

  const uint4* ap = (const uint4*)(A16 + (size_t)(m0 + srow) * KP + shalf * (KP / 2));
  const uint4* bp = (const uint4*)(B16 + (size_t)(n0 + srow) * KP + shalf * (KP / 2));
  uint4* aw = (uint4*)&As[srow * SB + shalf * (KP / 2)];
  uint4* bw = (uint4*)&Bs[srow * SB + shalf * (KP / 2)];
#pragma unroll
  for (int i = 0; i < KP / 16; i++) { aw[i] = ap[i]; bw[i] = bp[i]; }
  __syncthreads();

  constexpr int KC = KP / 32;
  f32x4 acc[4][4];
#pragma unroll
  for (int i = 0; i < 4; i++)
#pragma unroll
    for (int j = 0; j < 4; j++) acc[i][j] = (f32x4){0.f, 0.f, 0.f, 0.f};
#pragma unroll
  for (int ks = 0; ks < KC; ks++) {
    bf16x8 af[4], bfv[4];
#pragma unroll
    for (int mt = 0; mt < 4; mt++)
      af[mt] = *(const bf16x8*)&As[(wr * 64 + mt * 16 + lm) * SB + ks * 32 + lq * 8];
#pragma unroll
    for (int nt = 0; nt < 4; nt++)
      bfv[nt] = *(const bf16x8*)&Bs[(wc * 64 + nt * 16 + lm) * SB + ks * 32 + lq * 8];
#pragma unroll
    for (int mt = 0; mt < 4; mt++)
#pragma unroll
      for (int nt = 0; nt < 4; nt++)
        acc[mt][nt] = __builtin_amdgcn_mfma_f32_16x16x32_bf16(af[mt], bfv[nt], acc[mt][nt], 0, 0, 0);
  }
  float biasv[4];
#pragma unroll
  for (int nt = 0; nt < 4; nt++) {
    const int C = n0 + wc * 64 + nt * 16 + lm;
    biasv[nt] = bias[((C & 3) << LOG2H) + (C >> 2)];
  }
#pragma unroll
  for (int mt = 0; mt < 4; mt++) {
#pragma unroll
    for (int nt = 0; nt < 4; nt++) {
      const int row0 = m0 + wr * 64 + mt * 16 + lq * 4;
      const int col = n0 + wc * 64 + nt * 16 + lm;
#pragma unroll
      for (int r = 0; r < 4; r++)
        Y16[(size_t)(row0 + r) * 256 + col] = (ushortT)f2bf(acc[mt][nt][r] + biasv[nt]);
    }
  }
}

// --------------------- batched-MFMA LSTM recurrence (v5) --------------------
// Gate addends in registers: 4 coalesced dwordx2 loads per compute thread per
// step (each = 4 gates for one (batch,col)), prefetched ~2 steps ahead.
// LDS holds only the h-ring. lgkm-only barrier (no per-step vmcnt drain).
__device__ __forceinline__ void bar_lgkm() {
  asm volatile("s_waitcnt lgkmcnt(0)" ::: "memory");
  __builtin_amdgcn_sched_barrier(0);
  __builtin_amdgcn_s_barrier();
  __builtin_amdgcn_sched_barrier(0);
}

template <int H, int COFF, int CW>
__device__ __forceinline__ void recur_impl5(const ushortT* __restrict__ xp,   // [b][t][col][4]
                                            const ushortT* __restrict__ Whh, // [4H][H]
                                            ushortT* __restrict__ z,         // [B*T][256]
                                            int bblk, char* smem_) {
  constexpr int KC = H / 32;
  constexpr int C4H = 4 * H;
  constexpr int HP = H + 8;              // h-ring row stride
  constexpr int RING = 6;
  constexpr int CRB = H / 8;             // 16B runs per z row
  constexpr int FPT = (64 * CRB) / 512;  // flush uint4 per thread
  constexpr int RS = 256 * C4H;          // per-batch stride (ushorts)
  ushortT* hbuf = (ushortT*)smem_;       // [RING][16][HP]
  const int tid = threadIdx.x;
  const int s = tid >> 6, lane = tid & 63;
  const int lm = lane & 15, lq = lane >> 4;
  const int b0 = bblk * 16;
  const bool comp = (s < CW);
  // base for r=0: batch b0+lq*4, t=0, col=s*16+lm, gate 0
  const ushortT* xb = xp + (size_t)(b0 + lq * 4) * RS + (s * 16 + lm) * 4;

  bf16x8 bw[4][KC];
  if (comp) {
#pragma unroll
    for (int g = 0; g < 4; g++)
#pragma unroll
      for (int kc = 0; kc < KC; kc++) {
        const int n = g * H + s * 16 + lm;
        bw[g][kc] = *(const bf16x8*)(Whh + (size_t)n * H + kc * 32 + lq * 8);
      }
  }
  for (int i = tid; i < 16 * HP; i += 512) hbuf[(RING - 1) * 16 * HP + i] = 0;

  uint2 gA[4], gB[4];
  if (comp) {
#pragma unroll
    for (int r = 0; r < 4; r++) {
      gA[r] = *(const uint2*)(xb + (size_t)r * RS);
      gB[r] = *(const uint2*)(xb + (size_t)r * RS + C4H);
    }
  }
  float cst[4] = {0.f, 0.f, 0.f, 0.f};
  __syncthreads();

  // step t: extract gate addends from gCur; re-issue loads for t+2 into gCur
  // (~2 steps of slack); MFMA; activations; lgkm-only barrier.
  auto step = [&](int t, uint2 (&gCur)[4]) {
    // ---- flush h-ring to z (4 rows, wide stores), off the critical path ----
    if (t >= 4 && (t & 3) == 0) {
      const int t0 = t - 4;
#pragma unroll
      for (int i = 0; i < FPT; i++) {
        const int q = i * 512 + tid;
        const int m = q / (4 * CRB), j = (q / CRB) & 3, cr = q % CRB;
        const uint4 v = *(const uint4*)&hbuf[((t0 + j) % RING) * 16 * HP + m * HP + cr * 8];
        *(uint4*)&z[((size_t)(b0 + m) * 256 + t0 + j) * 256 + COFF + cr * 8] = v;
      }
    }
    if (comp) {
      // ---- extract 16 gate addends (4 gates x 4 batch rows) ----
      float ad[4][4];
#pragma unroll
      for (int r = 0; r < 4; r++) {
        const unsigned int w0 = gCur[r].x, w1 = gCur[r].y;
        ad[0][r] = __uint_as_float(w0 << 16);
        ad[1][r] = __uint_as_float(w0 & 0xffff0000u);
        ad[2][r] = __uint_as_float(w1 << 16);
        ad[3][r] = __uint_as_float(w1 & 0xffff0000u);
      }
      const int tn = (t + 2 < 256) ? t + 2 : 255;
#pragma unroll
      for (int r = 0; r < 4; r++)
        gCur[r] = *(const uint2*)(xb + (size_t)r * RS + (size_t)tn * C4H);
      // ---- gate GEMM ----
      const ushortT* hb = &hbuf[((t + RING - 1) % RING) * 16 * HP + lm * HP];
      bf16x8 af[KC];
#pragma unroll
      for (int kc = 0; kc < KC; kc++) af[kc] = *(const bf16x8*)(hb + kc * 32 + lq * 8);
      f32x4 acc[4];
#pragma unroll
      for (int g = 0; g < 4; g++) acc[g] = (f32x4){0.f, 0.f, 0.f, 0.f};
#pragma unroll
      for (int kc = 0; kc < KC; kc++)
#pragma unroll
        for (int g = 0; g < 4; g++)
          acc[g] = __builtin_amdgcn_mfma_f32_16x16x32_bf16(af[kc], bw[g][kc], acc[g], 0, 0, 0);
      // ---- activations (fused: 5 exp + 2 rcp per h) + h write ----
      ushortT* hw = &hbuf[(t % RING) * 16 * HP];
      const int col = s * 16 + lm;
#pragma unroll
      for (int r = 0; r < 4; r++) {
        const float iv = acc[0][r] + ad[0][r];
        const float fv = acc[1][r] + ad[1][r];
        const float gg = acc[2][r] + ad[2][r];
        const float ov = acc[3][r] + ad[3][r];
        const float ei = __expf(-iv), ef = __expf(-fv), eg = __expf(-2.f * gg);
        const float pi = 1.f + ei, pf = 1.f + ef, pg = 1.f + eg;
        const float cc = (cst[r] * pi * pg + (1.f - eg) * pf) *
                         __builtin_amdgcn_rcpf(pf * pi * pg);
        cst[r] = cc;
        const float ec = __expf(-2.f * cc), eo = __expf(-ov);
        const float hv = (1.f - ec) * __builtin_amdgcn_rcpf((1.f + eo) * (1.f + ec));
        hw[(lq * 4 + r) * HP + col] = (ushortT)f2bf(hv);
      }
    }
    // ---- lgkm-only barrier: no per-step vmcnt drain ----
    bar_lgkm();
  };

  for (int t = 0; t < 256; t += 2) {
    step(t, gA);
    step(t + 1, gB);
  }
  // final flush: z rows 252..255
  {
    const int t0 = 252;
#pragma unroll
    for (int i = 0; i < FPT; i++) {
      const int q = i * 512 + tid;
      const int m = q / (4 * CRB), j = (q / CRB) & 3, cr = q % CRB;
      const uint4 v = *(const uint4*)&hbuf[((t0 + j) % RING) * 16 * HP + m * HP + cr * 8];
      *(uint4*)&z[((size_t)(b0 + m) * 256 + t0 + j) * 256 + COFF + cr * 8] = v;
    }
  }
}

__global__ __launch_bounds__(512, 1) void recur5_k(const ushortT* __restrict__ xpt,
                                                   const ushortT* __restrict__ xpa,
                                                   const ushortT* __restrict__ xpv_,
                                                   const ushortT* __restrict__ Wt,
                                                   const ushortT* __restrict__ Wa,
                                                   const ushortT* __restrict__ Wv,
                                                   ushortT* __restrict__ z) {
  extern __shared__ char smem[];
  const int bid = blockIdx.x;
  if (bid < 16) recur_impl5<128, 128, 8>(xpt, Wt, z, bid, smem);
  else if (bid < 32) recur_impl5<64, 0, 4>(xpa, Wa, z, bid - 16, smem);
  else recur_impl5<64, 64, 4>(xpv_, Wv, z, bid - 32, smem);
}

// ------------------------------- fusion ------------------------------------
__global__ __launch_bounds__(192) void fusion_k(const ushortT* __restrict__ z,
                                                const float* __restrict__ W1,
                                                const float* __restrict__ b1,
                                                const float* __restrict__ W2,
                                                const float* __restrict__ b2,
                                                const float* __restrict__ fw,
                                                float* __restrict__ s_acc,
                                                float* __restrict__ sumsq) {
  __shared__ __align__(16) float zs[256 * 36];
  __shared__ float red[8];
  const int tid = threadIdx.x;
  const int b = blockIdx.x >> 3;
  const int t0 = (blockIdx.x & 7) * 32;
  const ushortT* zb = z + (size_t)b * 65536;
  float sq = 0.0f;
  for (int idx = tid; idx < 33 * 256; idx += 192) {
    const int row = idx >> 8, k = idx & 255;
    int t = t0 + row; if (t >= 256) t -= 256;
    const float v = bf2f(zb[t * 256 + k]);
    zs[k * 36 + row] = v;
    if (row < 32) sq += v * v;
  }
  __syncthreads();
  const int dg = tid >> 3;
  const int rg = tid & 7;
  const float* w1p = W1 + dg * 256;
  const float* w2p = W2 + dg * 513;
  float aa[4] = {}, ab1[4] = {}, ab2[4] = {};
#pragma unroll 4
  for (int k = 0; k < 256; k++) {
    const float w1v = w1p[k];
    const float w21 = w2p[1 + k];
    const float w22 = w2p[257 + k];
    const float* zr = &zs[k * 36 + (rg << 2)];
    const float4 za = *(const float4*)zr;
    const float z4 = zr[4];
    aa[0]  += za.x * w1v; aa[1]  += za.y * w1v; aa[2]  += za.z * w1v; aa[3]  += za.w * w1v;
    ab1[0] += za.x * w21; ab1[1] += za.y * w21; ab1[2] += za.z * w21; ab1[3] += za.w * w21;
    ab2[0] += za.y * w22; ab2[1] += za.z * w22; ab2[2] += za.w * w22; ab2[3] += z4   * w22;
  }
  const float b1v = b1[dg];
  const float b2v = b2[dg] + w2p[0];
  const float fwv = fw[dg];
  float s = 0.0f;
#pragma unroll
  for (int i = 0; i < 4; i++) {
    const float a  = aa[i] + b1v;
    const float bb = ab1[i] + ab2[i] + b2v;
    s += a * bb;
  }
  s *= fwv;
#pragma unroll
  for (int off = 32; off > 0; off >>= 1) {
    s  += __shfl_down(s, off);
    sq += __shfl_down(sq, off);
  }
  const int wid = tid >> 6;
  if ((tid & 63) == 0) { red[wid * 2] = s; red[wid * 2 + 1] = sq; }
  __syncthreads();
  if (tid == 0) {
    atomicAdd(&s_acc[b], red[0] + red[2] + red[4]);
    atomicAdd(&sumsq[b], red[1] + red[3] + red[5]);
  }
}

// ------------------------------- epilogue ----------------------------------
__global__ __launch_bounds__(256) void final_k(const float* __restrict__ s_acc,
                                               const float* __restrict__ sumsq,
                                               float* __restrict__ out) {
  __shared__ float red[4];
  const int tid = threadIdx.x;
  out[tid] = s_acc[tid] * (1.0f / 256.0f);
  float sq = sqrtf(sumsq[tid]);
#pragma unroll
  for (int off = 32; off > 0; off >>= 1) sq += __shfl_down(sq, off);
  if ((tid & 63) == 0) red[tid >> 6] = sq;
  __syncthreads();
  if (tid == 0) out[256] = (red[0] + red[1] + red[2] + red[3]) * (1.0f / 256.0f);
}

// ---------------------------------------------------------------------------
extern "C" void kernel_launch(void* const* d_in, const int* in_sizes, int n_in,
                              void* d_out, int out_size, void* d_ws, size_t ws_size,
                              hipStream_t stream) {
  const float* text   = (const float*)d_in[0];
  const float* audio  = (const float*)d_in[1];
  const float* vision = (const float*)d_in[2];
  const float* Wih_t  = (const float*)d_in[3];
  const float* Whh_t  = (const float*)d_in[4];
  const float* b_t    = (const float*)d_in[5];
  const float* Wih_a  = (const float*)d_in[6];
  const float* Whh_a  = (const float*)d_in[7];
  const float* b_a    = (const float*)d_in[8];
  const float* Wih_v  = (const float*)d_in[9];
  const float* Whh_v  = (const float*)d_in[10];
  const float* b_v    = (const float*)d_in[11];
  const float* W1     = (const float*)d_in[12];
  const float* b1     = (const float*)d_in[13];
  const float* W2     = (const float*)d_in[14];
  const float* b2     = (const float*)d_in[15];
  const float* fw     = (const float*)d_in[16];

  // workspace layout (bf16 elems unless noted)
  ushortT* xpt = (ushortT*)d_ws;               // 65536*512 ([b][t][col][4])
  ushortT* xpa = xpt + (size_t)33554432;       // 65536*256
  ushortT* xpv = xpa + (size_t)16777216;       // 65536*256
  ushortT* z16 = xpv + (size_t)16777216;       // 65536*256
  float* s_acc = (float*)(z16 + (size_t)16777216);  // 256 f32
  float* sumsq = s_acc + 256;                       // 256 f32
  ushortT* WhhT16 = (ushortT*)(sumsq + 256);   // 512*128
  ushortT* WhhA16 = WhhT16 + 65536;            // 256*64
  ushortT* WhhV16 = WhhA16 + 16384;            // 256*64
  // scratch aliased into z16 (fully consumed before recur5_k writes z):
  ushortT* A16a  = z16;                        // 65536*96
  ushortT* A16v  = A16a + (size_t)6291456;     // 65536*64
  ushortT* Wt768 = A16v + (size_t)4194304;     // 512*768 (row-permuted)
  ushortT* WA16  = Wt768 + 393216;             // 256*96  (row-permuted)
  ushortT* WV16  = WA16 + 24576;               // 256*64  (row-permuted)

  hipMemsetAsync(s_acc, 0, 512 * sizeof(float), stream);

  prep_k<<<43040, 256, 0, stream>>>(Wih_t, Whh_t, Wih_a, Whh_a, Wih_v, Whh_v,
                                    audio, vision,
                                    Wt768, WhhT16, WA16, WhhA16, WV16, WhhV16,
                                    A16a, A16v);

  gemm_text2_k<<<1024, 512, 0, stream>>>(text, Wt768, b_t, xpt);
  gemm_xp_k<96, 6><<<dim3(2, 512), 256, 0, stream>>>(A16a, WA16, b_a, xpa);
  gemm_xp_k<64, 6><<<dim3(2, 512), 256, 0, stream>>>(A16v, WV16, b_v, xpv);
  // dynamic LDS: h-ring only; text variant needs 6*16*136*2 = 26112 B
  recur5_k<<<48, 512, 26112, stream>>>(xpt, xpa, xpv, WhhT16, WhhA16, WhhV16, z16);
  fusion_k<<<2048, 192, 0, stream>>>(z16, W1, b1, W2, b2, fw, s_acc, sumsq);
  final_k<<<1, 256, 0, stream>>>(s_acc, sumsq, (float*)d_out);
}

// Round 6
// 750.497 us; speedup vs baseline: 1.2790x; 1.0195x over previous
//
#include <hip/hip_runtime.h>
#include <math.h>

// ---------------------------------------------------------------------------
// B=256, T=256, LEN=256 (audio 64 | vision 64 | text 128), RANK=24, EXT=513
// xp gate tensors: [b][t][col][gate] (gate innermost, 4 ushorts = 8B per
// (b,t,col)). Achieved by permuting Wih rows as n' = col*4 + gate, so the
// GEMM's dense epilogue Y[row*4H + n'] directly produces this layout.
// ---------------------------------------------------------------------------

typedef unsigned short ushortT;
typedef short bf16x8 __attribute__((ext_vector_type(8)));
typedef float f32x4 __attribute__((ext_vector_type(4)));

__device__ __forceinline__ unsigned int f2bf(float f) {  // RNE to bf16
  unsigned int u = __float_as_uint(f);
  u += 0x7FFFu + ((u >> 16) & 1u);
  return u >> 16;
}
__device__ __forceinline__ unsigned int pk2bf(float lo, float hi) {
  return f2bf(lo) | (f2bf(hi) << 16);
}
__device__ __forceinline__ float bf2f(ushortT u) {
  return __uint_as_float(((unsigned int)u) << 16);
}

// ------------------- unified prep: fp32->bf16 cvt (+pad, +row-perm) ---------
template <int KP, int KIN, int HR>
__device__ __forceinline__ void cvt_range(const float* __restrict__ src,
                                          ushortT* __restrict__ dst,
                                          int i, int total) {
  if (i >= total) return;
  if constexpr (HR == 0 && KP == KIN) {
    dst[i] = (ushortT)f2bf(src[i]);
  } else {
    const int row = i / KP, c = i - row * KP;
    const int srow = HR ? ((row & 3) * HR + (row >> 2)) : row;
    const float v = (c < KIN) ? src[(size_t)srow * KIN + c] : 0.f;
    dst[i] = (ushortT)f2bf(v);
  }
}

__global__ __launch_bounds__(256) void prep_k(
    const float* __restrict__ Wih_t, const float* __restrict__ Whh_t,
    const float* __restrict__ Wih_a, const float* __restrict__ Whh_a,
    const float* __restrict__ Wih_v, const float* __restrict__ Whh_v,
    const float* __restrict__ audio, const float* __restrict__ vision,
    const float* __restrict__ W2,
    ushortT* __restrict__ Wt768, ushortT* __restrict__ WhhT16,
    ushortT* __restrict__ WA16, ushortT* __restrict__ WhhA16,
    ushortT* __restrict__ WV16, ushortT* __restrict__ WhhV16,
    ushortT* __restrict__ A16a, ushortT* __restrict__ A16v,
    float* __restrict__ w2a, float* __restrict__ w2b, float* __restrict__ w2c) {
  const int b = blockIdx.x, tid = threadIdx.x;
  if (b < 1536)       cvt_range<768, 768, 128>(Wih_t, Wt768, b * 256 + tid, 393216);
  else if (b < 1792)  cvt_range<128, 128, 0>(Whh_t, WhhT16, (b - 1536) * 256 + tid, 65536);
  else if (b < 1856)  cvt_range<64, 64, 0>(Whh_a, WhhA16, (b - 1792) * 256 + tid, 16384);
  else if (b < 1920)  cvt_range<64, 64, 0>(Whh_v, WhhV16, (b - 1856) * 256 + tid, 16384);
  else if (b < 2016)  cvt_range<96, 74, 64>(Wih_a, WA16, (b - 1920) * 256 + tid, 24576);
  else if (b < 2080)  cvt_range<64, 35, 64>(Wih_v, WV16, (b - 2016) * 256 + tid, 16384);
  else if (b < 26656) cvt_range<96, 74, 0>(audio, A16a, (b - 2080) * 256 + tid, 6291456);
  else if (b < 43040) cvt_range<64, 35, 0>(vision, A16v, (b - 26656) * 256 + tid, 4194304);
  else {  // W2 repack: [24][513] -> w2c[24] | w2a[24][256] | w2b[24][256]
    const int i = (b - 43040) * 256 + tid;
    if (i < 12312) {
      const int dg = i / 513, c = i - dg * 513;
      const float v = W2[i];
      if (c == 0) w2c[dg] = v;
      else if (c <= 256) w2a[dg * 256 + c - 1] = v;
      else w2b[dg * 256 + c - 257] = v;
    }
  }
}

// ---------------- text input projection GEMM (bf16 MFMA, 128x256) -----------
// Y16[M=65536, 512] = bf16( X[M,768] @ W16[512,768]^T + bias[perm] ); W16 rows
// pre-permuted gate-innermost. Register-prefetch pipeline: tile k+1's global
// loads are issued between the LDS-commit of tile k and the compute barrier,
// giving them a full MFMA phase + barrier of slack.
#define SA2 40  // LDS row stride (BK=32 + 8 pad)
__global__ __launch_bounds__(512) void gemm_text2_k(const float* __restrict__ X,
                                                    const ushortT* __restrict__ W16,
                                                    const float* __restrict__ bias,
                                                    ushortT* __restrict__ Y16) {
  const int K = 768, N = 512;
  __shared__ __align__(16) ushortT As[128 * SA2];
  __shared__ __align__(16) ushortT Bs[256 * SA2];
  // n-siblings (same m-tile) at dispatch stride 8 -> same XCD -> A L2 reuse.
  const unsigned int lin = blockIdx.x;
  const int gb = (int)(lin >> 4), rb = (int)(lin & 15);
  const int m0 = (gb * 8 + (rb & 7)) * 128;
  const int n0 = (rb >> 3) * 256;
  const int tid = threadIdx.x;
  const int wave = tid >> 6, lane = tid & 63;
  const int wr = wave >> 2, wc = wave & 3;          // 2x4 wave grid (64x64 each)
  const int lm = lane & 15, lq = lane >> 4;
  const int arow = tid >> 2, aq = (tid & 3) * 8;    // A staging: 8 fp32/thread
  const int brow = tid >> 1, bq = (tid & 1) * 16;   // B staging: 16 bf16/thread

  const float*   Xp = X + (size_t)(m0 + arow) * K + aq;
  const ushortT* Wp = W16 + (size_t)(n0 + brow) * K + bq;
  uint4* As_w = (uint4*)&As[arow * SA2 + aq];
  uint4* Bs_w = (uint4*)&Bs[brow * SA2 + bq];

  f32x4 acc[4][4];
#pragma unroll
  for (int i = 0; i < 4; i++)
#pragma unroll
    for (int j = 0; j < 4; j++) acc[i][j] = (f32x4){0.f, 0.f, 0.f, 0.f};

  // prologue: load tile k=0
  float4 a0 = *(const float4*)(Xp);
  float4 a1 = *(const float4*)(Xp + 4);
  uint4 b0v = *(const uint4*)(Wp);
  uint4 b1v = *(const uint4*)(Wp + 8);

  for (int k0 = 0; k0 < K; k0 += 32) {
    __syncthreads();   // previous tile's readers done; LDS free
    uint4 ao;
    ao.x = pk2bf(a0.x, a0.y); ao.y = pk2bf(a0.z, a0.w);
    ao.z = pk2bf(a1.x, a1.y); ao.w = pk2bf(a1.z, a1.w);
    As_w[0] = ao;
    Bs_w[0] = b0v;
    Bs_w[1] = b1v;
    if (k0 + 32 < K) {  // prefetch tile k0+32 (consumed after next barrier)
      a0 = *(const float4*)(Xp + k0 + 32);
      a1 = *(const float4*)(Xp + k0 + 36);
      b0v = *(const uint4*)(Wp + k0 + 32);
      b1v = *(const uint4*)(Wp + k0 + 40);
    }
    __syncthreads();   // tile k0 visible in LDS
    bf16x8 af[4], bfv[4];
#pragma unroll
    for (int mt = 0; mt < 4; mt++)
      af[mt] = *(const bf16x8*)&As[(wr * 64 + mt * 16 + lm) * SA2 + lq * 8];
#pragma unroll
    for (int nt = 0; nt < 4; nt++)
      bfv[nt] = *(const bf16x8*)&Bs[(wc * 64 + nt * 16 + lm) * SA2 + lq * 8];
#pragma unroll
    for (int mt = 0; mt < 4; mt++)
#pragma unroll
      for (int nt = 0; nt < 4; nt++)
        acc[mt][nt] = __builtin_amdgcn_mfma_f32_16x16x32_bf16(af[mt], bfv[nt], acc[mt][nt], 0, 0, 0);
  }
  float biasv[4];
#pragma unroll
  for (int nt = 0; nt < 4; nt++) {
    const int C = n0 + wc * 64 + nt * 16 + lm;       // permuted col
    biasv[nt] = bias[((C & 3) << 7) + (C >> 2)];     // original gate-major idx
  }
#pragma unroll
  for (int mt = 0; mt < 4; mt++) {
#pragma unroll
    for (int nt = 0; nt < 4; nt++) {
      const int row0 = m0 + wr * 64 + mt * 16 + lq * 4;
      const int col = n0 + wc * 64 + nt * 16 + lm;
#pragma unroll
      for (int r = 0; r < 4; r++)
        Y16[(size_t)(row0 + r) * N + col] = (ushortT)f2bf(acc[mt][nt][r] + biasv[nt]);
    }
  }
}

// ------------- audio/vision input projection (small-K bf16 MFMA) ------------
template <int KP, int LOG2H>
__device__ __forceinline__ void gemm_xp_impl(const ushortT* __restrict__ A16,
                                             const ushortT* __restrict__ B16,
                                             const float* __restrict__ bias,
                                             ushortT* __restrict__ Y16,
                                             ushortT* As, ushortT* Bs) {
  constexpr int SB = KP + 8;
  const int n0 = blockIdx.x * 128;
  const int m0 = blockIdx.y * 128;
  const int tid = threadIdx.x;
  const int srow = tid >> 1, shalf = tid & 1;
  const int wave = tid >> 6, lane = tid & 63;
  const int wr = wave >> 1, wc = wave & 1;
  const int lm = lane & 15, lq = lane >> 4;

  const uint4* ap = (const uint4*)(A16 + (size_t)(m0 + srow) * KP + shalf * (KP / 2));
  const uint4* bp = (const uint4*)(B16 + (size_t)(n0 + srow) * KP + shalf * (KP / 2));
  uint4* aw = (uint4*)&As[srow * SB + shalf * (KP / 2)];
  uint4* bw = (uint4*)&Bs[srow * SB + shalf * (KP / 2)];
#pragma unroll
  for (int i = 0; i < KP / 16; i++) { aw[i] = ap[i]; bw[i] = bp[i]; }
  __syncthreads();

  constexpr int KC = KP / 32;
  f32x4 acc[4][4];
#pragma unroll
  for (int i = 0; i < 4; i++)
#pragma unroll
    for (int j = 0; j < 4; j++) acc[i][j] = (f32x4){0.f, 0.f, 0.f, 0.f};
#pragma unroll
  for (int ks = 0; ks < KC; ks++) {
    bf16x8 af[4], bfv[4];
#pragma unroll
    for (int mt = 0; mt < 4; mt++)
      af[mt] = *(const bf16x8*)&As[(wr * 64 + mt * 16 + lm) * SB + ks * 32 + lq * 8];
#pragma unroll
    for (int nt = 0; nt < 4; nt++)
      bfv[nt] = *(const bf16x8*)&Bs[(wc * 64 + nt * 16 + lm) * SB + ks * 32 + lq * 8];
#pragma unroll
    for (int mt = 0; mt < 4; mt++)
#pragma unroll
      for (int nt = 0; nt < 4; nt++)
        acc[mt][nt] = __builtin_amdgcn_mfma_f32_16x16x32_bf16(af[mt], bfv[nt], acc[mt][nt], 0, 0, 0);
  }
  float biasv[4];
#pragma unroll
  for (int nt = 0; nt < 4; nt++) {
    const int C = n0 + wc * 64 + nt * 16 + lm;
    biasv[nt] = bias[((C & 3) << LOG2H) + (C >> 2)];
  }
#pragma unroll
  for (int mt = 0; mt < 4; mt++) {
#pragma unroll
    for (int nt = 0; nt < 4; nt++) {
      const int row0 = m0 + wr * 64 + mt * 16 + lq * 4;
      const int col = n0 + wc * 64 + nt * 16 + lm;
#pragma unroll
      for (int r = 0; r < 4; r++)
        Y16[(size_t)(row0 + r) * 256 + col] = (ushortT)f2bf(acc[mt][nt][r] + biasv[nt]);
    }
  }
}

__global__ __launch_bounds__(256) void gemm_av_k(const ushortT* __restrict__ A16a,
                                                 const ushortT* __restrict__ WA16,
                                                 const float* __restrict__ b_a,
                                                 ushortT* __restrict__ xpa,
                                                 const ushortT* __restrict__ A16v,
                                                 const ushortT* __restrict__ WV16,
                                                 const float* __restrict__ b_v,
                                                 ushortT* __restrict__ xpv) {
  __shared__ __align__(16) ushortT As[128 * 104];
  __shared__ __align__(16) ushortT Bs[128 * 104];
  if (blockIdx.z == 0) gemm_xp_impl<96, 6>(A16a, WA16, b_a, xpa, As, Bs);
  else gemm_xp_impl<64, 6>(A16v, WV16, b_v, xpv, As, Bs);
}

// --------------------- batched-MFMA LSTM recurrence (v5) --------------------
// Gate addends in registers: 4 coalesced dwordx2 loads per compute thread per
// step (each = 4 gates for one (batch,col)), prefetched ~2 steps ahead.
// LDS holds only the h-ring. lgkm-only barrier (no per-step vmcnt drain).
__device__ __forceinline__ void bar_lgkm() {
  asm volatile("s_waitcnt lgkmcnt(0)" ::: "memory");
  __builtin_amdgcn_sched_barrier(0);
  __builtin_amdgcn_s_barrier();
  __builtin_amdgcn_sched_barrier(0);
}

template <int H, int COFF, int CW>
__device__ __forceinline__ void recur_impl5(const ushortT* __restrict__ xp,   // [b][t][col][4]
                                            const ushortT* __restrict__ Whh, // [4H][H]
                                            ushortT* __restrict__ z,         // [B*T][256]
                                            int bblk, char* smem_) {
  constexpr int KC = H / 32;
  constexpr int C4H = 4 * H;
  constexpr int HP = H + 8;              // h-ring row stride
  constexpr int RING = 6;
  constexpr int CRB = H / 8;             // 16B runs per z row
  constexpr int FPT = (64 * CRB) / 512;  // flush uint4 per thread
  constexpr int RS = 256 * C4H;          // per-batch stride (ushorts)
  ushortT* hbuf = (ushortT*)smem_;       // [RING][16][HP]
  const int tid = threadIdx.x;
  const int s = tid >> 6, lane = tid & 63;
  const int lm = lane & 15, lq = lane >> 4;
  const int b0 = bblk * 16;
  const bool comp = (s < CW);
  // base for r=0: batch b0+lq*4, t=0, col=s*16+lm, gate 0
  const ushortT* xb = xp + (size_t)(b0 + lq * 4) * RS + (s * 16 + lm) * 4;

  bf16x8 bw[4][KC];
  if (comp) {
#pragma unroll
    for (int g = 0; g < 4; g++)
#pragma unroll
      for (int kc = 0; kc < KC; kc++) {
        const int n = g * H + s * 16 + lm;
        bw[g][kc] = *(const bf16x8*)(Whh + (size_t)n * H + kc * 32 + lq * 8);
      }
  }
  for (int i = tid; i < 16 * HP; i += 512) hbuf[(RING - 1) * 16 * HP + i] = 0;

  uint2 gA[4], gB[4];
  if (comp) {
#pragma unroll
    for (int r = 0; r < 4; r++) {
      gA[r] = *(const uint2*)(xb + (size_t)r * RS);
      gB[r] = *(const uint2*)(xb + (size_t)r * RS + C4H);
    }
  }
  float cst[4] = {0.f, 0.f, 0.f, 0.f};
  __syncthreads();

  // step t: extract gate addends from gCur; re-issue loads for t+2 into gCur
  // (~2 steps of slack); MFMA; activations; lgkm-only barrier.
  auto step = [&](int t, uint2 (&gCur)[4]) {
    // ---- flush h-ring to z (4 rows, wide stores), off the critical path ----
    if (t >= 4 && (t & 3) == 0) {
      const int t0 = t - 4;
#pragma unroll
      for (int i = 0; i < FPT; i++) {
        const int q = i * 512 + tid;
        const int m = q / (4 * CRB), j = (q / CRB) & 3, cr = q % CRB;
        const uint4 v = *(const uint4*)&hbuf[((t0 + j) % RING) * 16 * HP + m * HP + cr * 8];
        *(uint4*)&z[((size_t)(b0 + m) * 256 + t0 + j) * 256 + COFF + cr * 8] = v;
      }
    }
    if (comp) {
      // ---- extract 16 gate addends (4 gates x 4 batch rows) ----
      float ad[4][4];
#pragma unroll
      for (int r = 0; r < 4; r++) {
        const unsigned int w0 = gCur[r].x, w1 = gCur[r].y;
        ad[0][r] = __uint_as_float(w0 << 16);
        ad[1][r] = __uint_as_float(w0 & 0xffff0000u);
        ad[2][r] = __uint_as_float(w1 << 16);
        ad[3][r] = __uint_as_float(w1 & 0xffff0000u);
      }
      const int tn = (t + 2 < 256) ? t + 2 : 255;
#pragma unroll
      for (int r = 0; r < 4; r++)
        gCur[r] = *(const uint2*)(xb + (size_t)r * RS + (size_t)tn * C4H);
      // ---- gate GEMM ----
      const ushortT* hb = &hbuf[((t + RING - 1) % RING) * 16 * HP + lm * HP];
      bf16x8 af[KC];
#pragma unroll
      for (int kc = 0; kc < KC; kc++) af[kc] = *(const bf16x8*)(hb + kc * 32 + lq * 8);
      f32x4 acc[4];
#pragma unroll
      for (int g = 0; g < 4; g++) acc[g] = (f32x4){0.f, 0.f, 0.f, 0.f};
#pragma unroll
      for (int kc = 0; kc < KC; kc++)
#pragma unroll
        for (int g = 0; g < 4; g++)
          acc[g] = __builtin_amdgcn_mfma_f32_16x16x32_bf16(af[kc], bw[g][kc], acc[g], 0, 0, 0);
      // ---- activations (fused: 5 exp + 2 rcp per h) + h write ----
      ushortT* hw = &hbuf[(t % RING) * 16 * HP];
      const int col = s * 16 + lm;
#pragma unroll
      for (int r = 0; r < 4; r++) {
        const float iv = acc[0][r] + ad[0][r];
        const float fv = acc[1][r] + ad[1][r];
        const float gg = acc[2][r] + ad[2][r];
        const float ov = acc[3][r] + ad[3][r];
        const float ei = __expf(-iv), ef = __expf(-fv), eg = __expf(-2.f * gg);
        const float pi = 1.f + ei, pf = 1.f + ef, pg = 1.f + eg;
        const float cc = (cst[r] * pi * pg + (1.f - eg) * pf) *
                         __builtin_amdgcn_rcpf(pf * pi * pg);
        cst[r] = cc;
        const float ec = __expf(-2.f * cc), eo = __expf(-ov);
        const float hv = (1.f - ec) * __builtin_amdgcn_rcpf((1.f + eo) * (1.f + ec));
        hw[(lq * 4 + r) * HP + col] = (ushortT)f2bf(hv);
      }
    }
    // ---- lgkm-only barrier: no per-step vmcnt drain ----
    bar_lgkm();
  };

  for (int t = 0; t < 256; t += 2) {
    step(t, gA);
    step(t + 1, gB);
  }
  // final flush: z rows 252..255
  {
    const int t0 = 252;
#pragma unroll
    for (int i = 0; i < FPT; i++) {
      const int q = i * 512 + tid;
      const int m = q / (4 * CRB), j = (q / CRB) & 3, cr = q % CRB;
      const uint4 v = *(const uint4*)&hbuf[((t0 + j) % RING) * 16 * HP + m * HP + cr * 8];
      *(uint4*)&z[((size_t)(b0 + m) * 256 + t0 + j) * 256 + COFF + cr * 8] = v;
    }
  }
}

__global__ __launch_bounds__(512, 1) void recur5_k(const ushortT* __restrict__ xpt,
                                                   const ushortT* __restrict__ xpa,
                                                   const ushortT* __restrict__ xpv_,
                                                   const ushortT* __restrict__ Wt,
                                                   const ushortT* __restrict__ Wa,
                                                   const ushortT* __restrict__ Wv,
                                                   ushortT* __restrict__ z) {
  extern __shared__ char smem[];
  const int bid = blockIdx.x;
  if (bid < 16) recur_impl5<128, 128, 8>(xpt, Wt, z, bid, smem);
  else if (bid < 32) recur_impl5<64, 0, 4>(xpa, Wa, z, bid - 16, smem);
  else recur_impl5<64, 64, 4>(xpv_, Wv, z, bid - 32, smem);
}

// ------------------------------- fusion ------------------------------------
// W2 pre-split into w2c (const col) + w2a/w2b (aligned 256-col panels) so the
// k-loop uses 3 aligned float4 loads per 4 iterations (4x fewer VMEM instrs).
__global__ __launch_bounds__(192) void fusion_k(const ushortT* __restrict__ z,
                                                const float* __restrict__ W1,
                                                const float* __restrict__ b1,
                                                const float* __restrict__ w2a,
                                                const float* __restrict__ w2b,
                                                const float* __restrict__ w2c,
                                                const float* __restrict__ b2,
                                                const float* __restrict__ fw,
                                                float* __restrict__ s_acc,
                                                float* __restrict__ sumsq) {
  __shared__ __align__(16) float zs[256 * 36];
  __shared__ float red[8];
  const int tid = threadIdx.x;
  const int b = blockIdx.x >> 3;
  const int t0 = (blockIdx.x & 7) * 32;
  const ushortT* zb = z + (size_t)b * 65536;
  float sq = 0.0f;
  for (int idx = tid; idx < 33 * 256; idx += 192) {
    const int row = idx >> 8, k = idx & 255;
    int t = t0 + row; if (t >= 256) t -= 256;
    const float v = bf2f(zb[t * 256 + k]);
    zs[k * 36 + row] = v;
    if (row < 32) sq += v * v;
  }
  __syncthreads();
  const int dg = tid >> 3;
  const int rg = tid & 7;
  const float* w1p = W1 + dg * 256;
  const float* w2ap = w2a + dg * 256;
  const float* w2bp = w2b + dg * 256;
  float aa[4] = {}, ab1[4] = {}, ab2[4] = {};
  for (int k = 0; k < 256; k += 4) {
    const float4 w1v4  = *(const float4*)(w1p + k);
    const float4 w21v4 = *(const float4*)(w2ap + k);
    const float4 w22v4 = *(const float4*)(w2bp + k);
#define FUS_STEP(J, W1C, W21C, W22C)                                   \
    {                                                                  \
      const float* zr = &zs[(k + J) * 36 + (rg << 2)];                 \
      const float4 za = *(const float4*)zr;                            \
      const float z4 = zr[4];                                          \
      aa[0] += za.x * (W1C); aa[1] += za.y * (W1C);                    \
      aa[2] += za.z * (W1C); aa[3] += za.w * (W1C);                    \
      ab1[0] += za.x * (W21C); ab1[1] += za.y * (W21C);                \
      ab1[2] += za.z * (W21C); ab1[3] += za.w * (W21C);                \
      ab2[0] += za.y * (W22C); ab2[1] += za.z * (W22C);                \
      ab2[2] += za.w * (W22C); ab2[3] += z4 * (W22C);                  \
    }
    FUS_STEP(0, w1v4.x, w21v4.x, w22v4.x)
    FUS_STEP(1, w1v4.y, w21v4.y, w22v4.y)
    FUS_STEP(2, w1v4.z, w21v4.z, w22v4.z)
    FUS_STEP(3, w1v4.w, w21v4.w, w22v4.w)
#undef FUS_STEP
  }
  const float b1v = b1[dg];
  const float b2v = b2[dg] + w2c[dg];
  const float fwv = fw[dg];
  float s = 0.0f;
#pragma unroll
  for (int i = 0; i < 4; i++) {
    const float a  = aa[i] + b1v;
    const float bb = ab1[i] + ab2[i] + b2v;
    s += a * bb;
  }
  s *= fwv;
#pragma unroll
  for (int off = 32; off > 0; off >>= 1) {
    s  += __shfl_down(s, off);
    sq += __shfl_down(sq, off);
  }
  const int wid = tid >> 6;
  if ((tid & 63) == 0) { red[wid * 2] = s; red[wid * 2 + 1] = sq; }
  __syncthreads();
  if (tid == 0) {
    atomicAdd(&s_acc[b], red[0] + red[2] + red[4]);
    atomicAdd(&sumsq[b], red[1] + red[3] + red[5]);
  }
}

// ------------------------------- epilogue ----------------------------------
__global__ __launch_bounds__(256) void final_k(const float* __restrict__ s_acc,
                                               const float* __restrict__ sumsq,
                                               float* __restrict__ out) {
  __shared__ float red[4];
  const int tid = threadIdx.x;
  out[tid] = s_acc[tid] * (1.0f / 256.0f);
  float sq = sqrtf(sumsq[tid]);
#pragma unroll
  for (int off = 32; off > 0; off >>= 1) sq += __shfl_down(sq, off);
  if ((tid & 63) == 0) red[tid >> 6] = sq;
  __syncthreads();
  if (tid == 0) out[256] = (red[0] + red[1] + red[2] + red[3]) * (1.0f / 256.0f);
}

// ---------------------------------------------------------------------------
extern "C" void kernel_launch(void* const* d_in, const int* in_sizes, int n_in,
                              void* d_out, int out_size, void* d_ws, size_t ws_size,
                              hipStream_t stream) {
  const float* text   = (const float*)d_in[0];
  const float* audio  = (const float*)d_in[1];
  const float* vision = (const float*)d_in[2];
  const float* Wih_t  = (const float*)d_in[3];
  const float* Whh_t  = (const float*)d_in[4];
  const float* b_t    = (const float*)d_in[5];
  const float* Wih_a  = (const float*)d_in[6];
  const float* Whh_a  = (const float*)d_in[7];
  const float* b_a    = (const float*)d_in[8];
  const float* Wih_v  = (const float*)d_in[9];
  const float* Whh_v  = (const float*)d_in[10];
  const float* b_v    = (const float*)d_in[11];
  const float* W1     = (const float*)d_in[12];
  const float* b1     = (const float*)d_in[13];
  const float* W2     = (const float*)d_in[14];
  const float* b2     = (const float*)d_in[15];
  const float* fw     = (const float*)d_in[16];

  // workspace layout (bf16 elems unless noted)
  ushortT* xpt = (ushortT*)d_ws;               // 65536*512 ([b][t][col][4])
  ushortT* xpa = xpt + (size_t)33554432;       // 65536*256
  ushortT* xpv = xpa + (size_t)16777216;       // 65536*256
  ushortT* z16 = xpv + (size_t)16777216;       // 65536*256
  float* s_acc = (float*)(z16 + (size_t)16777216);  // 256 f32
  float* sumsq = s_acc + 256;                       // 256 f32
  ushortT* WhhT16 = (ushortT*)(sumsq + 256);   // 512*128
  ushortT* WhhA16 = WhhT16 + 65536;            // 256*64
  ushortT* WhhV16 = WhhA16 + 16384;            // 256*64
  float* w2a = (float*)(WhhV16 + 16384);       // 24*256 f32
  float* w2b = w2a + 6144;                     // 24*256 f32
  float* w2c = w2b + 6144;                     // 24 f32
  // scratch aliased into z16 (fully consumed before recur5_k writes z):
  ushortT* A16a  = z16;                        // 65536*96
  ushortT* A16v  = A16a + (size_t)6291456;     // 65536*64
  ushortT* Wt768 = A16v + (size_t)4194304;     // 512*768 (row-permuted)
  ushortT* WA16  = Wt768 + 393216;             // 256*96  (row-permuted)
  ushortT* WV16  = WA16 + 24576;               // 256*64  (row-permuted)

  hipMemsetAsync(s_acc, 0, 512 * sizeof(float), stream);

  prep_k<<<43089, 256, 0, stream>>>(Wih_t, Whh_t, Wih_a, Whh_a, Wih_v, Whh_v,
                                    audio, vision, W2,
                                    Wt768, WhhT16, WA16, WhhA16, WV16, WhhV16,
                                    A16a, A16v, w2a, w2b, w2c);

  gemm_text2_k<<<1024, 512, 0, stream>>>(text, Wt768, b_t, xpt);
  gemm_av_k<<<dim3(2, 512, 2), 256, 0, stream>>>(A16a, WA16, b_a, xpa,
                                                 A16v, WV16, b_v, xpv);
  // dynamic LDS: h-ring only; text variant needs 6*16*136*2 = 26112 B
  recur5_k<<<48, 512, 26112, stream>>>(xpt, xpa, xpv, WhhT16, WhhA16, WhhV16, z16);
  fusion_k<<<2048, 192, 0, stream>>>(z16, W1, b1, w2a, w2b, w2c, b2, fw, s_acc, sumsq);
  final_k<<<1, 256, 0, stream>>>(s_acc, sumsq, (float*)d_out);
}